// Round 6
// baseline (755.806 us; speedup 1.0000x reference)
//
#include <hip/hip_runtime.h>
#include <math.h>

#define PI_D 3.14159265358979323846

constexpr int NBATCH = 8;
constexpr int NPTS   = 2048;
constexpr int F1C    = 100;
constexpr int F2C    = 100;

__host__ __device__ constexpr int S2c(int l){ return l*(2*l-1)*(2*l+1)/3; }

// ---- workspace layout (float offsets) ----
constexpr int OFF_WIN   = 0;                          // 60
constexpr int OFF_WMID  = OFF_WIN + 60;               // 32
constexpr int OFF_WOUTQ = OFF_WMID + 32;              // 20
constexpr int OFF_DM0W  = OFF_WOUTQ + 20;             // 60*256
constexpr int OFF_DMID  = OFF_DM0W + 60*256;          // 32*S2c(16)
constexpr int OFF_DOUT  = OFF_DMID + 32*S2c(16);      // 20*S2c(10)
constexpr int OFF_DEQ   = OFF_DOUT + 20*S2c(10);      // S2c(16)
constexpr int OFF_IMG   = OFF_DEQ + S2c(16);          // 8*60*60
constexpr int OFF_XF    = OFF_IMG + NBATCH*60*60;     // 8*60*31*2
constexpr int OFF_XHAT  = OFF_XF + NBATCH*60*31*2;    // 8*256*2
constexpr int OFF_WS2   = OFF_XHAT + NBATCH*256*2;    // 100*31*2
constexpr int OFF_BN1   = OFF_WS2 + 100*31*2;         // 200
constexpr int OFF_BN1AB = OFF_BN1 + 200;              // 200
constexpr int OFF_BN2   = OFF_BN1AB + 200;            // 200
constexpr int OFF_BN2AB = OFF_BN2 + 200;              // 200
constexpr int OFF_LUTA  = OFF_BN2AB + 200;            // 1330 ints
constexpr int OFF_LUTB  = OFF_LUTA + 1330;            // 1330 ints: xi | tl2<<9 | ni<<19
constexpr int OFF_WCONV = OFF_LUTB + 1330;            // WT[o][ni][i][2]
constexpr int OFF_XHAT2 = OFF_WCONV + 100*100*19*2;   // 8*100*1330*2
constexpr int OFF_SBUF  = OFF_XHAT2 + NBATCH*100*S2c(10)*2;  // ST[b][q][i][2]
constexpr int OFF_ZHAT2 = OFF_SBUF + NBATCH*100*S2c(10)*2;
constexpr int OFF_Z2    = OFF_ZHAT2 + NBATCH*100*S2c(10)*2;  // 8*100*8000
constexpr int OFF_Z     = OFF_Z2 + NBATCH*100*20*20*20;      // 8*100*32768
constexpr int WS_TOTAL  = OFF_Z + NBATCH*100*32*32*32;

__device__ __forceinline__ int S2d(int l){ return l*(2*l-1)*(2*l+1)/3; }

// ---------- init: quadrature weights ----------
__global__ void k_quad(float* ws){
  int j = threadIdx.x;
  if (j < 60){
    double bb = 30.0, s = 0.0;
    for (int k = 0; k < 30; ++k) s += sin(PI_D*(2*j+1)*(2*k+1)/(4.0*bb))/(2*k+1);
    ws[OFF_WIN+j] = (float)(2.0/bb * sin(PI_D*(2*j+1)/(4.0*bb)) * s);
  }
  if (j < 32){
    double bb = 16.0, s = 0.0;
    for (int k = 0; k < 16; ++k) s += sin(PI_D*(2*j+1)*(2*k+1)/(4.0*bb))/(2*k+1);
    ws[OFF_WMID+j] = (float)(2.0/bb * sin(PI_D*(2*j+1)/(4.0*bb)) * s);
  }
  if (j < 20){
    double bb = 10.0, s = 0.0;
    for (int k = 0; k < 10; ++k) s += sin(PI_D*(2*j+1)*(2*k+1)/(4.0*bb))/(2*k+1);
    ws[OFF_WOUTQ+j] = (float)(2.0/bb * sin(PI_D*(2*j+1)/(4.0*bb)) * s);
  }
}

// ---------- init: LUT ----------
__global__ void k_lut(float* ws){
  int q = blockIdx.x*blockDim.x + threadIdx.x;
  if (q >= 1330) return;
  int l = 0; while (S2d(l+1) <= q) ++l;
  int loc = q - S2d(l), tl = 2*l+1;
  int mm = loc/tl, nn = loc%tl;
  ((int*)(ws+OFF_LUTA))[q] = 32*S2d(l) + mm*tl + nn;
  ((int*)(ws+OFF_LUTB))[q] = ((mm-l+9)*19 + (nn-l+9)) | ((tl*tl) << 9) | ((nn-l+9) << 19);
}

// ---------- init: Wigner-d tables ----------
__device__ double dfact(int n){ double r = 1.0; for (int i = 2; i <= n; ++i) r *= (double)i; return r; }

__device__ double dev_wigner(int l, int mp, int m, double beta){
  double ch = cos(0.5*beta), sh = sin(0.5*beta);
  int kmin = m - mp; if (kmin < 0) kmin = 0;
  int kmax = l + m; if (l - mp < kmax) kmax = l - mp;
  double pref = sqrt(dfact(l+mp)*dfact(l-mp)*dfact(l+m)*dfact(l-m));
  double sum = 0.0;
  for (int k = kmin; k <= kmax; ++k){
    double t = 1.0/(dfact(l+m-k)*dfact(k)*dfact(l-mp-k)*dfact(mp-m+k));
    if ((mp-m+k) & 1) t = -t;
    int ec = 2*l+m-mp-2*k, es = mp-m+2*k;
    double cp = 1.0; for (int e = 0; e < ec; ++e) cp *= ch;
    double sp = 1.0; for (int e = 0; e < es; ++e) sp *= sh;
    sum += t*cp*sp;
  }
  return pref*sum;
}

constexpr int N_DM0W = 60*256;
constexpr int N_DMID = 32*S2c(16);
constexpr int N_DOUT = 20*S2c(10);
constexpr int N_DEQ  = S2c(16);
constexpr int N_WIG  = N_DM0W + N_DMID + N_DOUT + N_DEQ;

__global__ void k_wigner(float* ws){
  int idx = blockIdx.x*blockDim.x + threadIdx.x;
  if (idx >= N_WIG) return;
  if (idx < N_DM0W){
    int l = 0; while (60*(l+1)*(l+1) <= idx) ++l;
    int rem = idx - 60*l*l, tl = 2*l+1;
    int p = rem/tl, mm = rem%tl;
    double beta = (p+0.5)*PI_D/60.0;
    ws[OFF_DM0W+idx] = (float)dev_wigner(l, mm-l, 0, beta) * ws[OFF_WIN+p];
    return;
  }
  idx -= N_DM0W;
  if (idx < N_DMID){
    int l = 0; while (32*S2d(l+1) <= idx) ++l;
    int rem = idx - 32*S2d(l), tl = 2*l+1;
    int q = rem % (tl*tl), p = rem/(tl*tl);
    int mm = q/tl, nn = q%tl;
    double beta = (p+0.5)*PI_D/32.0;
    ws[OFF_DMID+idx] = (float)dev_wigner(l, mm-l, nn-l, beta);
    return;
  }
  idx -= N_DMID;
  if (idx < N_DOUT){
    int l = 0; while (20*S2d(l+1) <= idx) ++l;
    int rem = idx - 20*S2d(l), tl = 2*l+1;
    int q = rem % (tl*tl), p = rem/(tl*tl);
    int mm = q/tl, nn = q%tl;
    double beta = (p+0.5)*PI_D/20.0;
    ws[OFF_DOUT+idx] = (float)dev_wigner(l, mm-l, nn-l, beta);
    return;
  }
  idx -= N_DOUT;
  {
    int l = 0; while (S2d(l+1) <= idx) ++l;
    int rem = idx - S2d(l), tl = 2*l+1;
    int mm = rem/tl, nn = rem%tl;
    ws[OFF_DEQ+idx] = (float)dev_wigner(l, mm-l, nn-l, 0.5*PI_D);
  }
}

// ---------- 1. projection ----------
__global__ void k_project(const float* __restrict__ x, float* ws){
  int t = blockIdx.x*blockDim.x + threadIdx.x;
  if (t >= NBATCH*NPTS) return;
  int b = t / NPTS, n = t % NPTS;
  const float* xb = x + (size_t)b*3*NPTS;
  float xx = xb[n], yy = xb[NPTS+n], zz = xb[2*NPTS+n];
  float r = sqrtf(xx*xx + yy*yy + zz*zz + 1e-12f);
  float ct = zz / r;
  ct = fminf(fmaxf(ct, -1.0f + 1e-7f), 1.0f - 1e-7f);
  float beta = acosf(ct);
  float alpha = atan2f(yy, xx);
  if (alpha < 0.0f) alpha += 2.0f*(float)PI_D;
  int jb = (int)((beta / (float)PI_D) * 60.0f);
  jb = jb < 0 ? 0 : (jb > 59 ? 59 : jb);
  int ja = (int)((alpha / (2.0f*(float)PI_D)) * 60.0f);
  ja = ja < 0 ? 0 : (ja > 59 ? 59 : ja);
  unsigned* img = (unsigned*)(ws + OFF_IMG) + (b*3600 + jb*60 + ja);
  atomicMax(img, __float_as_uint(r));
}

// ---------- 2. S2 DFT over alpha ----------
__global__ void k_s2dft(float* ws){
  int t = blockIdx.x*blockDim.x + threadIdx.x;
  if (t >= NBATCH*60*31) return;
  int b = t/(60*31), r = t%(60*31);
  int p = r/31, mi = r%31, m = mi - 15;
  const float* img = ws + OFF_IMG + (b*60 + p)*60;
  float sr = 0.f, si = 0.f;
  for (int a = 0; a < 60; ++a){
    int k = ((a*m) % 60 + 60) % 60;
    float c = cospif(k/30.0f), s = sinpif(k/30.0f);
    float v = img[a];
    sr += v*c; si -= v*s;
  }
  ws[OFF_XF + t*2]   = sr;
  ws[OFF_XF + t*2+1] = si;
}

// ---------- 3. xhat ----------
__global__ void k_xhat(float* ws){
  int t = blockIdx.x*blockDim.x + threadIdx.x;
  if (t >= NBATCH*256) return;
  int b = t/256, flat = t%256;
  int l = 0; while ((l+1)*(l+1) <= flat) ++l;
  int mm = flat - l*l, tl = 2*l+1;
  int mi = mm - l + 15;
  float sr = 0.f, si = 0.f;
  for (int p = 0; p < 60; ++p){
    float w = ws[OFF_DM0W + 60*l*l + p*tl + mm];
    sr += w * ws[OFF_XF + ((b*60+p)*31 + mi)*2];
    si += w * ws[OFF_XF + ((b*60+p)*31 + mi)*2 + 1];
  }
  ws[OFF_XHAT + t*2]   = sr;
  ws[OFF_XHAT + t*2+1] = si;
}

// ---------- 3b. Ws2 ----------
__global__ void k_ws2(float* ws, const float* __restrict__ w_s2, float scale1){
  int t = blockIdx.x*blockDim.x + threadIdx.x;
  if (t >= 100*31) return;
  int o = t/31, ni = t%31, n = ni - 15;
  float sr = 0.f, si = 0.f;
  for (int k = 0; k < 60; ++k){
    int kk = ((k*n) % 60 + 60) % 60;
    float c = cospif(kk/30.0f), s = sinpif(kk/30.0f);
    float v = w_s2[o*60 + k] * scale1;
    sr += v*c; si += v*s;
  }
  ws[OFF_WS2 + t*2]   = sr;
  ws[OFF_WS2 + t*2+1] = si;
}

// ---------- 4. fused zhat + SO(3) IFFT (b=16), Hermitian + radix-4, full occupancy ----------
__global__ __launch_bounds__(256) void k_so3ifft_mid(float* ws, const float* __restrict__ b_s2){
  int bid = blockIdx.x;
  int p = bid & 31, bo = bid >> 5;
  int o = bo % F1C, b = bo / F1C;
  __shared__ float xh[512], Cc[512], Fg[992], tmpS[16*66];
  __shared__ float twr[32], twi[32], redA[4], redB[4];
  __shared__ int dbase[16];
  int tid = threadIdx.x;
  {
    int flat = tid;
    int l = 0; while ((l+1)*(l+1) <= flat) ++l;
    int mm = flat - l*l, tl = 2*l+1;
    xh[2*flat]   = ws[OFF_XHAT + (b*256+flat)*2];
    xh[2*flat+1] = ws[OFF_XHAT + (b*256+flat)*2+1];
    float deq0 = ws[OFF_DEQ + S2d(l) + mm*tl + l];
    int ni = mm - l + 15;
    float wr = ws[OFF_WS2 + (o*31+ni)*2], wi = ws[OFF_WS2 + (o*31+ni)*2+1];
    float f = (float)tl * deq0;
    Cc[2*flat] = f*wr; Cc[2*flat+1] = f*wi;
  }
  if (tid < 32){ twr[tid] = cospif(tid/16.0f); twi[tid] = sinpif(tid/16.0f); }
  if (tid < 16){ int l = tid, tl = 2*l+1; dbase[l] = OFF_DMID + 32*S2d(l) + p*tl*tl; }
  __syncthreads();
  // Fg[m][ni], m=0..15 (Hermitian)
  for (int q = tid; q < 496; q += 256){
    int m = q/31, ni = q%31, n = ni-15;
    int an = n < 0 ? -n : n;
    int lmin = m > an ? m : an;
    float ar = 0.f, ai = 0.f;
    for (int l = lmin; l < 16; ++l){
      int tl = 2*l+1;
      float d = ws[dbase[l] + (m+l)*tl + (n+l)];
      int fa = l*l + (m+l), fc = l*l + (n+l);
      float xr = xh[2*fa], xi = xh[2*fa+1];
      float cr = Cc[2*fc], ci = Cc[2*fc+1];
      ar += d*(xr*cr - xi*ci);
      ai += d*(xr*ci + xi*cr);
    }
    Fg[2*q] = ar; Fg[2*q+1] = ai;
  }
  __syncthreads();
  // alpha-pass radix-4, 256 threads: lane pairs split ni by parity, shfl-combine.
  // class(ni) = (ni+1)&3:  ni%4==0 ->T1, 2->T3, 1->T2, 3->T0
  {
    int w = tid >> 1, half = tid & 1;
    int m = w >> 3, g0 = w & 7;
    float T0r=0,T0i=0,T1r=0,T1i=0,T2r=0,T2i=0,T3r=0,T3i=0;
    int base = 2*m*31;
    if (half == 0){
      #pragma unroll
      for (int ni = 0; ni < 31; ni += 4){
        int k = ((ni-15)*g0) & 31;
        float c = twr[k], s = twi[k];
        float fr = Fg[base+2*ni], fi = Fg[base+2*ni+1];
        T1r += fr*c - fi*s; T1i += fr*s + fi*c;
      }
      #pragma unroll
      for (int ni = 2; ni < 31; ni += 4){
        int k = ((ni-15)*g0) & 31;
        float c = twr[k], s = twi[k];
        float fr = Fg[base+2*ni], fi = Fg[base+2*ni+1];
        T3r += fr*c - fi*s; T3i += fr*s + fi*c;
      }
    } else {
      #pragma unroll
      for (int ni = 1; ni < 31; ni += 4){
        int k = ((ni-15)*g0) & 31;
        float c = twr[k], s = twi[k];
        float fr = Fg[base+2*ni], fi = Fg[base+2*ni+1];
        T2r += fr*c - fi*s; T2i += fr*s + fi*c;
      }
      #pragma unroll
      for (int ni = 3; ni < 31; ni += 4){
        int k = ((ni-15)*g0) & 31;
        float c = twr[k], s = twi[k];
        float fr = Fg[base+2*ni], fi = Fg[base+2*ni+1];
        T0r += fr*c - fi*s; T0i += fr*s + fi*c;
      }
    }
    T0r += __shfl_xor(T0r,1); T0i += __shfl_xor(T0i,1);
    T1r += __shfl_xor(T1r,1); T1i += __shfl_xor(T1i,1);
    T2r += __shfl_xor(T2r,1); T2i += __shfl_xor(T2i,1);
    T3r += __shfl_xor(T3r,1); T3i += __shfl_xor(T3i,1);
    if (half == 0){
      float Ar=T0r+T2r, Ai=T0i+T2i, Br=T0r-T2r, Bi=T0i-T2i;
      float Cr=T1r+T3r, Ci=T1i+T3i, Dr=T1r-T3r, Di=T1i-T3i;
      int ix = m*66 + 2*g0;
      tmpS[ix]      = Ar+Cr; tmpS[ix+1]    = Ai+Ci;   // s=0
      tmpS[ix+16]   = Br-Di; tmpS[ix+17]   = Bi+Dr;   // s=1
      tmpS[ix+32]   = Ar-Cr; tmpS[ix+33]   = Ai-Ci;   // s=2
      tmpS[ix+48]   = Br+Di; tmpS[ix+49]   = Bi-Dr;   // s=3
    }
  }
  __syncthreads();
  // gamma-pass radix-4: a = a0 + 8t, 4 outputs per thread
  float bsv = b_s2[o];
  float lsum = 0.f, lss = 0.f;
  float* z = ws + OFF_Z;
  size_t zb = ((size_t)(b*F1C+o)*32 + p)*1024;
  {
    int a0 = tid >> 5, g = tid & 31;
    float U0r=0, U2r=0, U1r=0, U1i=0, U3r=0, U3i=0;
    #pragma unroll
    for (int m = 1; m < 16; ++m){
      int k = (m*a0) & 31;
      float c = twr[k], s = twi[k];
      float tr = tmpS[m*66+2*g], ti = tmpS[m*66+2*g+1];
      float re = tr*c - ti*s;
      int cc = m & 3;
      if (cc == 0) U0r += re;
      else if (cc == 2) U2r += re;
      else {
        float im = tr*s + ti*c;
        if (cc == 1){ U1r += re; U1i += im; }
        else        { U3r += re; U3i += im; }
      }
    }
    float Ar = U0r + U2r, Br = U0r - U2r;
    float Cr = U1r + U3r, Di = U1i - U3i;
    float t0 = tmpS[2*g];
    float v0 = (t0 + 2.0f*(Ar + Cr))*(1.0f/1024.0f) + bsv;
    float v1 = (t0 + 2.0f*(Br - Di))*(1.0f/1024.0f) + bsv;
    float v2 = (t0 + 2.0f*(Ar - Cr))*(1.0f/1024.0f) + bsv;
    float v3 = (t0 + 2.0f*(Br + Di))*(1.0f/1024.0f) + bsv;
    z[zb + (a0     )*32 + g] = v0;
    z[zb + (a0 +  8)*32 + g] = v1;
    z[zb + (a0 + 16)*32 + g] = v2;
    z[zb + (a0 + 24)*32 + g] = v3;
    lsum = v0+v1+v2+v3;
    lss  = v0*v0+v1*v1+v2*v2+v3*v3;
  }
  for (int off = 32; off; off >>= 1){ lsum += __shfl_down(lsum, off); lss += __shfl_down(lss, off); }
  if ((tid & 63) == 0){ redA[tid>>6] = lsum; redB[tid>>6] = lss; }
  __syncthreads();
  if (tid == 0){
    atomicAdd(&ws[OFF_BN1 + o],       redA[0]+redA[1]+redA[2]+redA[3]);
    atomicAdd(&ws[OFF_BN1 + 100 + o], redB[0]+redB[1]+redB[2]+redB[3]);
  }
}

__global__ void k_bnfin1(float* ws, const float* __restrict__ g1, const float* __restrict__ be1){
  int t = threadIdx.x;
  if (t >= 100) return;
  const float invN = 1.0f/262144.0f;
  float mu = ws[OFF_BN1+t]*invN;
  float var = ws[OFF_BN1+100+t]*invN - mu*mu;
  float sA = rsqrtf(var + 1e-5f) * g1[t];
  ws[OFF_BN1AB+t]     = sA;
  ws[OFF_BN1AB+100+t] = be1[t] - mu*sA;
}

// ---------- 6a. BN1+ReLU + 2D DFT: radix-4 gamma (conj trick), radix-2 alpha ----------
__global__ __launch_bounds__(256) void k_so3fft_a(float* ws){
  int bid = blockIdx.x;
  int p = bid & 31, bo = bid >> 5;
  int o = bo % F1C;
  __shared__ float y[32*33];
  __shared__ float Bs[32*36];     // per a: [g2*4 + {c0,c2,c1r,c1i}]
  __shared__ float t1[1216];
  __shared__ float twr[32], twi[32];
  int tid = threadIdx.x;
  if (tid < 32){ twr[tid] = cospif(tid/16.0f); twi[tid] = sinpif(tid/16.0f); }
  float sA = ws[OFF_BN1AB+o], sB = ws[OFF_BN1AB+100+o];
  float* zp = ws + OFF_Z + (size_t)bid*1024;
  for (int q = tid; q < 1024; q += 256){
    float v = zp[q]*sA + sB;
    y[(q>>5)*33 + (q&31)] = v > 0.f ? v : 0.f;
  }
  __syncthreads();
  // radix-4 prep over g: B_c[g2], c3 = conj(c1)
  {
    int a = tid >> 3, g2 = tid & 7;
    float y0 = y[a*33+g2], y1 = y[a*33+g2+8], y2 = y[a*33+g2+16], y3 = y[a*33+g2+24];
    float e = y0+y2, f = y1+y3;
    int bb = a*36 + g2*4;
    Bs[bb]   = e+f;          // c0
    Bs[bb+1] = e-f;          // c2
    Bs[bb+2] = y0-y2;        // c1r
    Bs[bb+3] = -(y1-y3);     // c1i
  }
  __syncthreads();
  // t1[a][ni] = sum_{g2=0..7} e^{-2pi i g2 n/32} * B_{n mod 4}[g2]
  for (int q = tid; q < 608; q += 256){
    int a = q/19, ni = q%19, n = ni-9;
    int c = n & 3;
    int bb = a*36;
    float sr = 0.f, si = 0.f;
    if ((c & 1) == 0){
      int off = bb + (c >> 1);
      #pragma unroll
      for (int g2 = 0; g2 < 8; ++g2){
        int k = (g2*n) & 31;
        float B = Bs[off + g2*4];
        sr += B*twr[k]; si -= B*twi[k];
      }
    } else {
      float sgn = (c == 1) ? 1.f : -1.f;
      #pragma unroll
      for (int g2 = 0; g2 < 8; ++g2){
        int k = (g2*n) & 31;
        float cc_ = twr[k], ss = twi[k];
        float br = Bs[bb+g2*4+2], bi = sgn*Bs[bb+g2*4+3];
        sr += br*cc_ + bi*ss;
        si += bi*cc_ - br*ss;
      }
    }
    t1[2*q] = sr; t1[2*q+1] = si;
  }
  __syncthreads();
  // butterfly over a: t1[a] <- S, t1[a+16] <- D
  for (int q = tid; q < 304; q += 256){
    int a = q/19, ni = q%19;
    int i0 = 2*(a*19+ni), i1 = 2*((a+16)*19+ni);
    float xr=t1[i0], xi=t1[i0+1], yr=t1[i1], yi=t1[i1+1];
    t1[i0]=xr+yr; t1[i0+1]=xi+yi; t1[i1]=xr-yr; t1[i1+1]=xi-yi;
  }
  __syncthreads();
  // X2w rows m=0..9; m even uses S-half, m odd uses D-half; mirror m<0
  float wm = ws[OFF_WMID+p];
  for (int q = tid; q < 190; q += 256){
    int m = q/19, ni = q%19;
    int off = (m & 1) ? 16*19 : 0;
    float sr = 0.f, si = 0.f;
    for (int a = 0; a < 16; ++a){
      int k = (a*m) & 31;
      float c = twr[k], s = twi[k];
      float tr = t1[2*(off+a*19+ni)], ti = t1[2*(off+a*19+ni)+1];
      sr += tr*c + ti*s;
      si += ti*c - tr*s;
    }
    sr *= wm; si *= wm;
    int qf = (m+9)*19 + ni;
    zp[2*qf] = sr; zp[2*qf+1] = si;
    if (m > 0){
      int qm = (9-m)*19 + (18-ni);
      zp[2*qm] = sr; zp[2*qm+1] = -si;
    }
  }
}

// ---------- 6b. Wigner beta-projection, LDS-staged ----------
__global__ __launch_bounds__(256) void k_so3fft_b(float* ws){
  int bo = blockIdx.x;
  int tid = threadIdx.x;
  __shared__ float xw[722];
  const float* xwbase = ws + OFF_Z + (size_t)bo*32*1024;
  const int* lutA = (const int*)(ws + OFF_LUTA);
  const int* lutB = (const int*)(ws + OFF_LUTB);
  float accr[6], acci[6];
  int la[6], xi2[6], tl2v[6];
  #pragma unroll
  for (int j = 0; j < 6; ++j){
    accr[j] = 0.f; acci[j] = 0.f;
    int q = tid + 256*j;
    if (q < 1330){ la[j] = lutA[q]; int lb = lutB[q]; xi2[j] = 2*(lb & 511); tl2v[j] = (lb >> 9) & 1023; }
    else { la[j] = 0; xi2[j] = 0; tl2v[j] = 0; }
  }
  for (int pp = 0; pp < 32; ++pp){
    __syncthreads();
    for (int u = tid; u < 722; u += 256) xw[u] = xwbase[pp*1024 + u];
    __syncthreads();
    #pragma unroll
    for (int j = 0; j < 6; ++j){
      int q = tid + 256*j;
      if (q < 1330){
        float d = ws[OFF_DMID + la[j] + pp*tl2v[j]];
        accr[j] += d*xw[xi2[j]]; acci[j] += d*xw[xi2[j]+1];
      }
    }
  }
  #pragma unroll
  for (int j = 0; j < 6; ++j){
    int q = tid + 256*j;
    if (q < 1330){
      int base = OFF_XHAT2 + (bo*1330 + q)*2;
      ws[base]   = accr[j];
      ws[base+1] = acci[j];
    }
  }
}

// ---------- 7a. WT[o][ni][i], i-innermost (coalesced writes) ----------
__global__ void k_wconv(float* ws, const float* __restrict__ w_so3, float scale2){
  int t = blockIdx.x*blockDim.x + threadIdx.x;
  if (t >= 100*19*100) return;
  int i = t % 100, rem = t / 100;
  int ni = rem % 19, o = rem / 19;
  int n = ni - 9;
  float sr = 0.f, si = 0.f;
  for (int j = 0; j < 32; ++j){
    int k = (j*n) & 31;
    float c = cospif(k/16.0f), s = sinpif(k/16.0f);
    float v = w_so3[(i*100+o)*32 + j] * scale2;
    sr += v*c; si += v*s;
  }
  int base = OFF_WCONV + ((o*19 + ni)*100 + i)*2;
  ws[base]   = sr;
  ws[base+1] = si;
}

// ---------- 7b. ST[b][q][i], i-innermost (coalesced writes) ----------
__global__ void k_S(float* ws){
  int t = blockIdx.x*blockDim.x + threadIdx.x;
  if (t >= NBATCH*1330*100) return;
  int i = t % 100, rem = t / 100;
  int q = rem % 1330, b = rem / 1330;
  int l = 0; while (S2d(l+1) <= q) ++l;
  int loc = q - S2d(l), tl = 2*l+1;
  int mm = loc/tl, nn = loc%tl;
  float sr = 0.f, si = 0.f;
  int xbase = OFF_XHAT2 + ((b*100+i)*1330 + S2d(l) + mm*tl)*2;
  int dbase = OFF_DEQ + S2d(l) + nn*tl;
  for (int k = 0; k < tl; ++k){
    float d = ws[dbase + k];
    sr += d * ws[xbase + 2*k];
    si += d * ws[xbase + 2*k + 1];
  }
  int base = OFF_SBUF + ((b*1330 + q)*100 + i)*2;
  ws[base]   = sr;
  ws[base+1] = si;
}

// ---------- 7c. zhat2: 4 o's per thread, float4 streams ----------
__global__ __launch_bounds__(256) void k_zhat2(float* ws){
  int t = blockIdx.x*blockDim.x + threadIdx.x;
  if (t >= NBATCH*1330*25) return;
  int oq = t % 25, q = (t/25) % 1330, b = t/(25*1330);
  int lb = ((const int*)(ws+OFF_LUTB))[q];
  int ni = (lb >> 19) & 31;
  const float4* sp  = (const float4*)(ws + OFF_SBUF + (size_t)(b*1330+q)*200);
  int o0 = oq*4;
  const float4* wp0 = (const float4*)(ws + OFF_WCONV + (size_t)((o0  )*19+ni)*200);
  const float4* wp1 = (const float4*)(ws + OFF_WCONV + (size_t)((o0+1)*19+ni)*200);
  const float4* wp2 = (const float4*)(ws + OFF_WCONV + (size_t)((o0+2)*19+ni)*200);
  const float4* wp3 = (const float4*)(ws + OFF_WCONV + (size_t)((o0+3)*19+ni)*200);
  float r0=0,i0=0,r1=0,i1=0,r2=0,i2=0,r3=0,i3=0;
  for (int u = 0; u < 50; ++u){
    float4 s = sp[u];
    float4 w;
    w = wp0[u];
    r0 += s.x*w.x - s.y*w.y + s.z*w.z - s.w*w.w;
    i0 += s.x*w.y + s.y*w.x + s.z*w.w + s.w*w.z;
    w = wp1[u];
    r1 += s.x*w.x - s.y*w.y + s.z*w.z - s.w*w.w;
    i1 += s.x*w.y + s.y*w.x + s.z*w.w + s.w*w.z;
    w = wp2[u];
    r2 += s.x*w.x - s.y*w.y + s.z*w.z - s.w*w.w;
    i2 += s.x*w.y + s.y*w.x + s.z*w.w + s.w*w.z;
    w = wp3[u];
    r3 += s.x*w.x - s.y*w.y + s.z*w.z - s.w*w.w;
    i3 += s.x*w.y + s.y*w.x + s.z*w.w + s.w*w.z;
  }
  int zb = OFF_ZHAT2 + ((b*100 + o0)*1330 + q)*2;
  ws[zb]            = r0; ws[zb+1]          = i0;
  ws[zb+2660]       = r1; ws[zb+2661]       = i1;
  ws[zb+2*2660]     = r2; ws[zb+2*2660+1]   = i2;
  ws[zb+3*2660]     = r3; ws[zb+3*2660+1]   = i3;
}

// ---------- 8. SO(3) IFFT (b=10), Hermitian + radix-2 ----------
__global__ __launch_bounds__(256) void k_so3ifft_out(float* ws, const float* __restrict__ b_so3){
  int bid = blockIdx.x;
  int p = bid % 20, bo = bid / 20;
  int o = bo % F2C, b = bo / F2C;
  __shared__ __align__(16) float zh[2660];
  __shared__ float Fg[380], tmpS[400];
  __shared__ float twr[20], twi[20], redA[4], redB[4];
  int tid = threadIdx.x;
  {
    const float4* zsrc = (const float4*)(ws + OFF_ZHAT2 + (size_t)(b*100+o)*2660);
    float4* zds = (float4*)zh;
    for (int q = tid; q < 665; q += 256) zds[q] = zsrc[q];
  }
  if (tid < 20){ twr[tid] = cospif(tid/10.0f); twi[tid] = sinpif(tid/10.0f); }
  __syncthreads();
  for (int q = tid; q < 190; q += 256){
    int m = q/19, ni = q%19, n = ni-9;
    int an = n < 0 ? -n : n;
    int lmin = m > an ? m : an;
    float ar = 0.f, ai = 0.f;
    for (int l = lmin; l < 10; ++l){
      int tl = 2*l+1;
      float d = ws[OFF_DOUT + 20*S2d(l) + (p*tl + (m+l))*tl + (n+l)] * (float)tl;
      int fz = S2d(l) + (m+l)*tl + (n+l);
      ar += d*zh[2*fz]; ai += d*zh[2*fz+1];
    }
    Fg[2*q] = ar; Fg[2*q+1] = ai;
  }
  __syncthreads();
  for (int q = tid; q < 100; q += 256){
    int m = q/10, g = q%10;
    float Er=0.f, Ei=0.f, Or=0.f, Oi=0.f;
    int base = 2*m*19;
    for (int ni = 1; ni < 19; ni += 2){
      int n = ni-9;
      int k = ((n*g) % 20 + 20) % 20;
      float c = twr[k], s = twi[k];
      float fr = Fg[base+2*ni], fi = Fg[base+2*ni+1];
      Er += fr*c - fi*s; Ei += fr*s + fi*c;
    }
    for (int ni = 0; ni < 19; ni += 2){
      int n = ni-9;
      int k = ((n*g) % 20 + 20) % 20;
      float c = twr[k], s = twi[k];
      float fr = Fg[base+2*ni], fi = Fg[base+2*ni+1];
      Or += fr*c - fi*s; Oi += fr*s + fi*c;
    }
    tmpS[2*(m*20+g)]      = Er+Or; tmpS[2*(m*20+g)+1]      = Ei+Oi;
    tmpS[2*(m*20+g+10)]   = Er-Or; tmpS[2*(m*20+g+10)+1]   = Ei-Oi;
  }
  __syncthreads();
  float bsv = b_so3[o];
  float lsum = 0.f, lss = 0.f;
  float* z2 = ws + OFF_Z2;
  size_t zb = ((size_t)(b*100+o)*20 + p)*400;
  for (int q = tid; q < 200; q += 256){
    int a = q/20, g = q%20;
    float E = 0.f, O = 0.f;
    for (int m = 2; m < 10; m += 2){
      int k = (m*a) % 20;
      E += tmpS[2*(m*20+g)]*twr[k] - tmpS[2*(m*20+g)+1]*twi[k];
    }
    for (int m = 1; m < 10; m += 2){
      int k = (m*a) % 20;
      O += tmpS[2*(m*20+g)]*twr[k] - tmpS[2*(m*20+g)+1]*twi[k];
    }
    float t0 = tmpS[2*g];
    float v1 = (t0 + 2.0f*(E+O))*(1.0f/400.0f) + bsv;
    float v2 = (t0 + 2.0f*(E-O))*(1.0f/400.0f) + bsv;
    z2[zb + a*20 + g]       = v1;
    z2[zb + (a+10)*20 + g]  = v2;
    lsum += v1+v2; lss += v1*v1+v2*v2;
  }
  for (int off = 32; off; off >>= 1){ lsum += __shfl_down(lsum, off); lss += __shfl_down(lss, off); }
  if ((tid & 63) == 0){ redA[tid>>6] = lsum; redB[tid>>6] = lss; }
  __syncthreads();
  if (tid == 0){
    atomicAdd(&ws[OFF_BN2 + o],       redA[0]+redA[1]+redA[2]+redA[3]);
    atomicAdd(&ws[OFF_BN2 + 100 + o], redB[0]+redB[1]+redB[2]+redB[3]);
  }
}

__global__ void k_bnfin2(float* ws, const float* __restrict__ g2, const float* __restrict__ be2){
  int t = threadIdx.x;
  if (t >= 100) return;
  const float invN = 1.0f/64000.0f;
  float mu = ws[OFF_BN2+t]*invN;
  float var = ws[OFF_BN2+100+t]*invN - mu*mu;
  float sA = rsqrtf(var + 1e-5f) * g2[t];
  ws[OFF_BN2AB+t]     = sA;
  ws[OFF_BN2AB+100+t] = be2[t] - mu*sA;
}

// ---------- 9. final pooling ----------
__global__ __launch_bounds__(256) void k_final(float* ws, float* __restrict__ out){
  int bid = blockIdx.x;
  int c = bid % 100, b = bid / 100;
  int tid = threadIdx.x;
  float sA = ws[OFF_BN2AB+c], sB = ws[OFF_BN2AB+100+c];
  const float* z2 = ws + OFF_Z2 + (size_t)(b*100+c)*8000;
  float lsum = 0.f;
  for (int q = tid; q < 8000; q += 256){
    int p = q / 400;
    float v = z2[q]*sA + sB;
    v = v > 0.f ? v : 0.f;
    lsum += v * ws[OFF_WOUTQ + p];
  }
  for (int off = 32; off; off >>= 1) lsum += __shfl_down(lsum, off);
  __shared__ float red[4];
  if ((tid & 63) == 0) red[tid>>6] = lsum;
  __syncthreads();
  if (tid == 0) out[b*100 + c] = red[0]+red[1]+red[2]+red[3];
}

extern "C" void kernel_launch(void* const* d_in, const int* in_sizes, int n_in,
                              void* d_out, int out_size, void* d_ws, size_t ws_size,
                              hipStream_t stream){
  const float* x      = (const float*)d_in[0];
  const float* w_s2   = (const float*)d_in[1];
  const float* b_s2   = (const float*)d_in[2];
  const float* g1     = (const float*)d_in[3];
  const float* be1    = (const float*)d_in[4];
  const float* w_so3  = (const float*)d_in[5];
  const float* b_so3  = (const float*)d_in[6];
  const float* g2     = (const float*)d_in[7];
  const float* be2    = (const float*)d_in[8];
  float* ws  = (float*)d_ws;
  float* out = (float*)d_out;

  hipMemsetAsync(ws + OFF_IMG, 0, NBATCH*3600*sizeof(float), stream);
  hipMemsetAsync(ws + OFF_BN1, 0, 200*sizeof(float), stream);
  hipMemsetAsync(ws + OFF_BN2, 0, 200*sizeof(float), stream);

  k_quad<<<1, 128, 0, stream>>>(ws);
  k_lut<<<6, 256, 0, stream>>>(ws);
  k_wigner<<<(N_WIG + 255)/256, 256, 0, stream>>>(ws);
  k_project<<<(NBATCH*NPTS + 255)/256, 256, 0, stream>>>(x, ws);
  k_s2dft<<<(NBATCH*60*31 + 255)/256, 256, 0, stream>>>(ws);
  k_xhat<<<(NBATCH*256 + 255)/256, 256, 0, stream>>>(ws);
  float scale1 = (float)(1.0/sqrt(60.0*1.0*65536.0/900.0));
  k_ws2<<<(100*31 + 255)/256, 256, 0, stream>>>(ws, w_s2, scale1);
  k_so3ifft_mid<<<NBATCH*F1C*32, 256, 0, stream>>>(ws, b_s2);
  k_bnfin1<<<1, 128, 0, stream>>>(ws, g1, be1);
  k_so3fft_a<<<NBATCH*F1C*32, 256, 0, stream>>>(ws);
  k_so3fft_b<<<NBATCH*F1C, 256, 0, stream>>>(ws);
  float scale2 = (float)(1.0/sqrt(32.0*100.0*1000.0/4096.0));
  k_wconv<<<(100*19*100 + 255)/256, 256, 0, stream>>>(ws, w_so3, scale2);
  k_S<<<(NBATCH*1330*100 + 255)/256, 256, 0, stream>>>(ws);
  k_zhat2<<<(NBATCH*1330*25 + 255)/256, 256, 0, stream>>>(ws);
  k_so3ifft_out<<<NBATCH*F2C*20, 256, 0, stream>>>(ws, b_so3);
  k_bnfin2<<<1, 128, 0, stream>>>(ws, g2, be2);
  k_final<<<NBATCH*100, 256, 0, stream>>>(ws, out);
}

// Round 7
// 672.327 us; speedup vs baseline: 1.1242x; 1.1242x over previous
//
#include <hip/hip_runtime.h>
#include <math.h>

#define PI_D 3.14159265358979323846

constexpr int NBATCH = 8;
constexpr int NPTS   = 2048;
constexpr int F1C    = 100;
constexpr int F2C    = 100;

__host__ __device__ constexpr int S2c(int l){ return l*(2*l-1)*(2*l+1)/3; }

// ---- workspace layout (float offsets) ----
constexpr int OFF_WIN   = 0;                          // 60
constexpr int OFF_WMID  = OFF_WIN + 60;               // 32
constexpr int OFF_WOUTQ = OFF_WMID + 32;              // 20
constexpr int OFF_DM0W  = OFF_WOUTQ + 20;             // 60*256
constexpr int OFF_DMID  = OFF_DM0W + 60*256;          // 32*S2c(16)
constexpr int OFF_DOUT  = OFF_DMID + 32*S2c(16);      // 20*S2c(10)
constexpr int OFF_DEQ   = OFF_DOUT + 20*S2c(10);      // S2c(16)
constexpr int OFF_IMG   = OFF_DEQ + S2c(16);          // 8*60*60
constexpr int OFF_XF    = OFF_IMG + NBATCH*60*60;     // 8*60*31*2
constexpr int OFF_XHAT  = OFF_XF + NBATCH*60*31*2;    // 8*256*2
constexpr int OFF_WS2   = OFF_XHAT + NBATCH*256*2;    // 100*31*2
constexpr int OFF_BN1   = OFF_WS2 + 100*31*2;         // 200
constexpr int OFF_BN1AB = OFF_BN1 + 200;              // 200
constexpr int OFF_BN2   = OFF_BN1AB + 200;            // 200
constexpr int OFF_BN2AB = OFF_BN2 + 200;              // 200
constexpr int OFF_LUTA  = OFF_BN2AB + 200;            // 1330 ints
constexpr int OFF_LUTB  = OFF_LUTA + 1330;            // 1330 ints: xi | tl2<<9 | ni<<19
constexpr int OFF_WCONV = OFF_LUTB + 1330;            // W[i][o][ni][2]
constexpr int OFF_XHAT2 = OFF_WCONV + 100*100*19*2;   // 8*100*1330*2
constexpr int OFF_SBUF  = OFF_XHAT2 + NBATCH*100*S2c(10)*2;  // S[b][i][q][2]
constexpr int OFF_ZHAT2 = OFF_SBUF + NBATCH*100*S2c(10)*2;
constexpr int OFF_Z2    = OFF_ZHAT2 + NBATCH*100*S2c(10)*2;  // 8*100*8000
constexpr int OFF_Z     = OFF_Z2 + NBATCH*100*20*20*20;      // 8*100*32768
constexpr int WS_TOTAL  = OFF_Z + NBATCH*100*32*32*32;

__device__ __forceinline__ int S2d(int l){ return l*(2*l-1)*(2*l+1)/3; }

// ---------- init: quadrature weights ----------
__global__ void k_quad(float* ws){
  int j = threadIdx.x;
  if (j < 60){
    double bb = 30.0, s = 0.0;
    for (int k = 0; k < 30; ++k) s += sin(PI_D*(2*j+1)*(2*k+1)/(4.0*bb))/(2*k+1);
    ws[OFF_WIN+j] = (float)(2.0/bb * sin(PI_D*(2*j+1)/(4.0*bb)) * s);
  }
  if (j < 32){
    double bb = 16.0, s = 0.0;
    for (int k = 0; k < 16; ++k) s += sin(PI_D*(2*j+1)*(2*k+1)/(4.0*bb))/(2*k+1);
    ws[OFF_WMID+j] = (float)(2.0/bb * sin(PI_D*(2*j+1)/(4.0*bb)) * s);
  }
  if (j < 20){
    double bb = 10.0, s = 0.0;
    for (int k = 0; k < 10; ++k) s += sin(PI_D*(2*j+1)*(2*k+1)/(4.0*bb))/(2*k+1);
    ws[OFF_WOUTQ+j] = (float)(2.0/bb * sin(PI_D*(2*j+1)/(4.0*bb)) * s);
  }
}

// ---------- init: LUT ----------
__global__ void k_lut(float* ws){
  int q = blockIdx.x*blockDim.x + threadIdx.x;
  if (q >= 1330) return;
  int l = 0; while (S2d(l+1) <= q) ++l;
  int loc = q - S2d(l), tl = 2*l+1;
  int mm = loc/tl, nn = loc%tl;
  ((int*)(ws+OFF_LUTA))[q] = 32*S2d(l) + mm*tl + nn;
  ((int*)(ws+OFF_LUTB))[q] = ((mm-l+9)*19 + (nn-l+9)) | ((tl*tl) << 9) | ((nn-l+9) << 19);
}

// ---------- init: Wigner-d tables ----------
__device__ double dfact(int n){ double r = 1.0; for (int i = 2; i <= n; ++i) r *= (double)i; return r; }

__device__ double dev_wigner(int l, int mp, int m, double beta){
  double ch = cos(0.5*beta), sh = sin(0.5*beta);
  int kmin = m - mp; if (kmin < 0) kmin = 0;
  int kmax = l + m; if (l - mp < kmax) kmax = l - mp;
  double pref = sqrt(dfact(l+mp)*dfact(l-mp)*dfact(l+m)*dfact(l-m));
  double sum = 0.0;
  for (int k = kmin; k <= kmax; ++k){
    double t = 1.0/(dfact(l+m-k)*dfact(k)*dfact(l-mp-k)*dfact(mp-m+k));
    if ((mp-m+k) & 1) t = -t;
    int ec = 2*l+m-mp-2*k, es = mp-m+2*k;
    double cp = 1.0; for (int e = 0; e < ec; ++e) cp *= ch;
    double sp = 1.0; for (int e = 0; e < es; ++e) sp *= sh;
    sum += t*cp*sp;
  }
  return pref*sum;
}

constexpr int N_DM0W = 60*256;
constexpr int N_DMID = 32*S2c(16);
constexpr int N_DOUT = 20*S2c(10);
constexpr int N_DEQ  = S2c(16);
constexpr int N_WIG  = N_DM0W + N_DMID + N_DOUT + N_DEQ;

__global__ void k_wigner(float* ws){
  int idx = blockIdx.x*blockDim.x + threadIdx.x;
  if (idx >= N_WIG) return;
  if (idx < N_DM0W){
    int l = 0; while (60*(l+1)*(l+1) <= idx) ++l;
    int rem = idx - 60*l*l, tl = 2*l+1;
    int p = rem/tl, mm = rem%tl;
    double beta = (p+0.5)*PI_D/60.0;
    ws[OFF_DM0W+idx] = (float)dev_wigner(l, mm-l, 0, beta) * ws[OFF_WIN+p];
    return;
  }
  idx -= N_DM0W;
  if (idx < N_DMID){
    int l = 0; while (32*S2d(l+1) <= idx) ++l;
    int rem = idx - 32*S2d(l), tl = 2*l+1;
    int q = rem % (tl*tl), p = rem/(tl*tl);
    int mm = q/tl, nn = q%tl;
    double beta = (p+0.5)*PI_D/32.0;
    ws[OFF_DMID+idx] = (float)dev_wigner(l, mm-l, nn-l, beta);
    return;
  }
  idx -= N_DMID;
  if (idx < N_DOUT){
    int l = 0; while (20*S2d(l+1) <= idx) ++l;
    int rem = idx - 20*S2d(l), tl = 2*l+1;
    int q = rem % (tl*tl), p = rem/(tl*tl);
    int mm = q/tl, nn = q%tl;
    double beta = (p+0.5)*PI_D/20.0;
    ws[OFF_DOUT+idx] = (float)dev_wigner(l, mm-l, nn-l, beta);
    return;
  }
  idx -= N_DOUT;
  {
    int l = 0; while (S2d(l+1) <= idx) ++l;
    int rem = idx - S2d(l), tl = 2*l+1;
    int mm = rem/tl, nn = rem%tl;
    ws[OFF_DEQ+idx] = (float)dev_wigner(l, mm-l, nn-l, 0.5*PI_D);
  }
}

// ---------- 1. projection ----------
__global__ void k_project(const float* __restrict__ x, float* ws){
  int t = blockIdx.x*blockDim.x + threadIdx.x;
  if (t >= NBATCH*NPTS) return;
  int b = t / NPTS, n = t % NPTS;
  const float* xb = x + (size_t)b*3*NPTS;
  float xx = xb[n], yy = xb[NPTS+n], zz = xb[2*NPTS+n];
  float r = sqrtf(xx*xx + yy*yy + zz*zz + 1e-12f);
  float ct = zz / r;
  ct = fminf(fmaxf(ct, -1.0f + 1e-7f), 1.0f - 1e-7f);
  float beta = acosf(ct);
  float alpha = atan2f(yy, xx);
  if (alpha < 0.0f) alpha += 2.0f*(float)PI_D;
  int jb = (int)((beta / (float)PI_D) * 60.0f);
  jb = jb < 0 ? 0 : (jb > 59 ? 59 : jb);
  int ja = (int)((alpha / (2.0f*(float)PI_D)) * 60.0f);
  ja = ja < 0 ? 0 : (ja > 59 ? 59 : ja);
  unsigned* img = (unsigned*)(ws + OFF_IMG) + (b*3600 + jb*60 + ja);
  atomicMax(img, __float_as_uint(r));
}

// ---------- 2. S2 DFT over alpha ----------
__global__ void k_s2dft(float* ws){
  int t = blockIdx.x*blockDim.x + threadIdx.x;
  if (t >= NBATCH*60*31) return;
  int b = t/(60*31), r = t%(60*31);
  int p = r/31, mi = r%31, m = mi - 15;
  const float* img = ws + OFF_IMG + (b*60 + p)*60;
  float sr = 0.f, si = 0.f;
  for (int a = 0; a < 60; ++a){
    int k = ((a*m) % 60 + 60) % 60;
    float c = cospif(k/30.0f), s = sinpif(k/30.0f);
    float v = img[a];
    sr += v*c; si -= v*s;
  }
  ws[OFF_XF + t*2]   = sr;
  ws[OFF_XF + t*2+1] = si;
}

// ---------- 3. xhat ----------
__global__ void k_xhat(float* ws){
  int t = blockIdx.x*blockDim.x + threadIdx.x;
  if (t >= NBATCH*256) return;
  int b = t/256, flat = t%256;
  int l = 0; while ((l+1)*(l+1) <= flat) ++l;
  int mm = flat - l*l, tl = 2*l+1;
  int mi = mm - l + 15;
  float sr = 0.f, si = 0.f;
  for (int p = 0; p < 60; ++p){
    float w = ws[OFF_DM0W + 60*l*l + p*tl + mm];
    sr += w * ws[OFF_XF + ((b*60+p)*31 + mi)*2];
    si += w * ws[OFF_XF + ((b*60+p)*31 + mi)*2 + 1];
  }
  ws[OFF_XHAT + t*2]   = sr;
  ws[OFF_XHAT + t*2+1] = si;
}

// ---------- 3b. Ws2 ----------
__global__ void k_ws2(float* ws, const float* __restrict__ w_s2, float scale1){
  int t = blockIdx.x*blockDim.x + threadIdx.x;
  if (t >= 100*31) return;
  int o = t/31, ni = t%31, n = ni - 15;
  float sr = 0.f, si = 0.f;
  for (int k = 0; k < 60; ++k){
    int kk = ((k*n) % 60 + 60) % 60;
    float c = cospif(kk/30.0f), s = sinpif(kk/30.0f);
    float v = w_s2[o*60 + k] * scale1;
    sr += v*c; si += v*s;
  }
  ws[OFF_WS2 + t*2]   = sr;
  ws[OFF_WS2 + t*2+1] = si;
}

// ---------- 4. fused zhat + SO(3) IFFT (b=16), Hermitian + radix-4 (R4 128-thread alpha) ----------
__global__ __launch_bounds__(256) void k_so3ifft_mid(float* ws, const float* __restrict__ b_s2){
  int bid = blockIdx.x;
  int p = bid & 31, bo = bid >> 5;
  int o = bo % F1C, b = bo / F1C;
  __shared__ float xh[512], Cc[512], Fg[992], tmpS[1024];
  __shared__ float twr[32], twi[32], redA[4], redB[4];
  __shared__ int dbase[16];
  int tid = threadIdx.x;
  {
    int flat = tid;
    int l = 0; while ((l+1)*(l+1) <= flat) ++l;
    int mm = flat - l*l, tl = 2*l+1;
    xh[2*flat]   = ws[OFF_XHAT + (b*256+flat)*2];
    xh[2*flat+1] = ws[OFF_XHAT + (b*256+flat)*2+1];
    float deq0 = ws[OFF_DEQ + S2d(l) + mm*tl + l];
    int ni = mm - l + 15;
    float wr = ws[OFF_WS2 + (o*31+ni)*2], wi = ws[OFF_WS2 + (o*31+ni)*2+1];
    float f = (float)tl * deq0;
    Cc[2*flat] = f*wr; Cc[2*flat+1] = f*wi;
  }
  if (tid < 32){ twr[tid] = cospif(tid/16.0f); twi[tid] = sinpif(tid/16.0f); }
  if (tid < 16){ int l = tid, tl = 2*l+1; dbase[l] = OFF_DMID + 32*S2d(l) + p*tl*tl; }
  __syncthreads();
  // Fg[m][ni], m=0..15 (Hermitian)
  for (int q = tid; q < 496; q += 256){
    int m = q/31, ni = q%31, n = ni-15;
    int an = n < 0 ? -n : n;
    int lmin = m > an ? m : an;
    float ar = 0.f, ai = 0.f;
    for (int l = lmin; l < 16; ++l){
      int tl = 2*l+1;
      float d = ws[dbase[l] + (m+l)*tl + (n+l)];
      int fa = l*l + (m+l), fc = l*l + (n+l);
      float xr = xh[2*fa], xi = xh[2*fa+1];
      float cr = Cc[2*fc], ci = Cc[2*fc+1];
      ar += d*(xr*cr - xi*ci);
      ai += d*(xr*ci + xi*cr);
    }
    Fg[2*q] = ar; Fg[2*q+1] = ai;
  }
  __syncthreads();
  // alpha-pass radix-4: g = g0 + 8s, w^{8n} = i^n. 128 threads: (m, g0).
  if (tid < 128){
    int m = tid >> 3, g0 = tid & 7;
    float T0r=0,T0i=0,T1r=0,T1i=0,T2r=0,T2i=0,T3r=0,T3i=0;
    int base = 2*m*31;
    #pragma unroll
    for (int ni = 0; ni < 31; ++ni){
      int k = ((ni-15)*g0) & 31;
      float c = twr[k], s = twi[k];
      float fr = Fg[base+2*ni], fi = Fg[base+2*ni+1];
      float re = fr*c - fi*s, im = fr*s + fi*c;
      int cc = (ni+1) & 3;                    // n mod 4
      if (cc == 0){ T0r += re; T0i += im; }
      else if (cc == 1){ T1r += re; T1i += im; }
      else if (cc == 2){ T2r += re; T2i += im; }
      else { T3r += re; T3i += im; }
    }
    float Ar=T0r+T2r, Ai=T0i+T2i, Br=T0r-T2r, Bi=T0i-T2i;
    float Cr=T1r+T3r, Ci=T1i+T3i, Dr=T1r-T3r, Di=T1i-T3i;
    int ix = 2*(m*32+g0);
    tmpS[ix]        = Ar+Cr; tmpS[ix+1]      = Ai+Ci;   // s=0
    tmpS[ix+16]     = Br-Di; tmpS[ix+17]     = Bi+Dr;   // s=1: B+iD
    tmpS[ix+32]     = Ar-Cr; tmpS[ix+33]     = Ai-Ci;   // s=2
    tmpS[ix+48]     = Br+Di; tmpS[ix+49]     = Bi-Dr;   // s=3: B-iD
  }
  __syncthreads();
  // gamma-pass radix-4: a = a0 + 8t. 256 threads: (a0, g); 4 outputs each.
  float bsv = b_s2[o];
  float lsum = 0.f, lss = 0.f;
  float* z = ws + OFF_Z;
  size_t zb = ((size_t)(b*F1C+o)*32 + p)*1024;
  {
    int a0 = tid >> 5, g = tid & 31;
    float U0r=0, U2r=0, U1r=0, U1i=0, U3r=0, U3i=0;
    #pragma unroll
    for (int m = 1; m < 16; ++m){
      int k = (m*a0) & 31;
      float c = twr[k], s = twi[k];
      float tr = tmpS[2*(m*32+g)], ti = tmpS[2*(m*32+g)+1];
      float re = tr*c - ti*s;
      int cc = m & 3;
      if (cc == 0) U0r += re;
      else if (cc == 2) U2r += re;
      else {
        float im = tr*s + ti*c;
        if (cc == 1){ U1r += re; U1i += im; }
        else        { U3r += re; U3i += im; }
      }
    }
    float Ar = U0r + U2r, Br = U0r - U2r;
    float Cr = U1r + U3r, Di = U1i - U3i;
    float t0 = tmpS[2*g];
    float v0 = (t0 + 2.0f*(Ar + Cr))*(1.0f/1024.0f) + bsv;
    float v1 = (t0 + 2.0f*(Br - Di))*(1.0f/1024.0f) + bsv;
    float v2 = (t0 + 2.0f*(Ar - Cr))*(1.0f/1024.0f) + bsv;
    float v3 = (t0 + 2.0f*(Br + Di))*(1.0f/1024.0f) + bsv;
    z[zb + (a0     )*32 + g] = v0;
    z[zb + (a0 +  8)*32 + g] = v1;
    z[zb + (a0 + 16)*32 + g] = v2;
    z[zb + (a0 + 24)*32 + g] = v3;
    lsum = v0+v1+v2+v3;
    lss  = v0*v0+v1*v1+v2*v2+v3*v3;
  }
  for (int off = 32; off; off >>= 1){ lsum += __shfl_down(lsum, off); lss += __shfl_down(lss, off); }
  if ((tid & 63) == 0){ redA[tid>>6] = lsum; redB[tid>>6] = lss; }
  __syncthreads();
  if (tid == 0){
    atomicAdd(&ws[OFF_BN1 + o],       redA[0]+redA[1]+redA[2]+redA[3]);
    atomicAdd(&ws[OFF_BN1 + 100 + o], redB[0]+redB[1]+redB[2]+redB[3]);
  }
}

__global__ void k_bnfin1(float* ws, const float* __restrict__ g1, const float* __restrict__ be1){
  int t = threadIdx.x;
  if (t >= 100) return;
  const float invN = 1.0f/262144.0f;
  float mu = ws[OFF_BN1+t]*invN;
  float var = ws[OFF_BN1+100+t]*invN - mu*mu;
  float sA = rsqrtf(var + 1e-5f) * g1[t];
  ws[OFF_BN1AB+t]     = sA;
  ws[OFF_BN1AB+100+t] = be1[t] - mu*sA;
}

// ---------- 6a. BN1+ReLU + 2D DFT: radix-4 gamma (conj trick), radix-2 alpha ----------
__global__ __launch_bounds__(256) void k_so3fft_a(float* ws){
  int bid = blockIdx.x;
  int p = bid & 31, bo = bid >> 5;
  int o = bo % F1C;
  __shared__ float y[32*33];
  __shared__ float Bs[32*36];     // per a: [g2*4 + {c0,c2,c1r,c1i}]
  __shared__ float t1[1216];
  __shared__ float twr[32], twi[32];
  int tid = threadIdx.x;
  if (tid < 32){ twr[tid] = cospif(tid/16.0f); twi[tid] = sinpif(tid/16.0f); }
  float sA = ws[OFF_BN1AB+o], sB = ws[OFF_BN1AB+100+o];
  float* zp = ws + OFF_Z + (size_t)bid*1024;
  for (int q = tid; q < 1024; q += 256){
    float v = zp[q]*sA + sB;
    y[(q>>5)*33 + (q&31)] = v > 0.f ? v : 0.f;
  }
  __syncthreads();
  // radix-4 prep over g: B_c[g2], c3 = conj(c1)
  {
    int a = tid >> 3, g2 = tid & 7;
    float y0 = y[a*33+g2], y1 = y[a*33+g2+8], y2 = y[a*33+g2+16], y3 = y[a*33+g2+24];
    float e = y0+y2, f = y1+y3;
    int bb = a*36 + g2*4;
    Bs[bb]   = e+f;          // c0
    Bs[bb+1] = e-f;          // c2
    Bs[bb+2] = y0-y2;        // c1r
    Bs[bb+3] = -(y1-y3);     // c1i
  }
  __syncthreads();
  // t1[a][ni] = sum_{g2=0..7} e^{-2pi i g2 n/32} * B_{n mod 4}[g2]
  for (int q = tid; q < 608; q += 256){
    int a = q/19, ni = q%19, n = ni-9;
    int c = n & 3;
    int bb = a*36;
    float sr = 0.f, si = 0.f;
    if ((c & 1) == 0){
      int off = bb + (c >> 1);
      #pragma unroll
      for (int g2 = 0; g2 < 8; ++g2){
        int k = (g2*n) & 31;
        float B = Bs[off + g2*4];
        sr += B*twr[k]; si -= B*twi[k];
      }
    } else {
      float sgn = (c == 1) ? 1.f : -1.f;
      #pragma unroll
      for (int g2 = 0; g2 < 8; ++g2){
        int k = (g2*n) & 31;
        float cc_ = twr[k], ss = twi[k];
        float br = Bs[bb+g2*4+2], bi = sgn*Bs[bb+g2*4+3];
        sr += br*cc_ + bi*ss;
        si += bi*cc_ - br*ss;
      }
    }
    t1[2*q] = sr; t1[2*q+1] = si;
  }
  __syncthreads();
  // butterfly over a: t1[a] <- S, t1[a+16] <- D
  for (int q = tid; q < 304; q += 256){
    int a = q/19, ni = q%19;
    int i0 = 2*(a*19+ni), i1 = 2*((a+16)*19+ni);
    float xr=t1[i0], xi=t1[i0+1], yr=t1[i1], yi=t1[i1+1];
    t1[i0]=xr+yr; t1[i0+1]=xi+yi; t1[i1]=xr-yr; t1[i1+1]=xi-yi;
  }
  __syncthreads();
  // X2w rows m=0..9; m even uses S-half, m odd uses D-half; mirror m<0
  float wm = ws[OFF_WMID+p];
  for (int q = tid; q < 190; q += 256){
    int m = q/19, ni = q%19;
    int off = (m & 1) ? 16*19 : 0;
    float sr = 0.f, si = 0.f;
    for (int a = 0; a < 16; ++a){
      int k = (a*m) & 31;
      float c = twr[k], s = twi[k];
      float tr = t1[2*(off+a*19+ni)], ti = t1[2*(off+a*19+ni)+1];
      sr += tr*c + ti*s;
      si += ti*c - tr*s;
    }
    sr *= wm; si *= wm;
    int qf = (m+9)*19 + ni;
    zp[2*qf] = sr; zp[2*qf+1] = si;
    if (m > 0){
      int qm = (9-m)*19 + (18-ni);
      zp[2*qm] = sr; zp[2*qm+1] = -si;
    }
  }
}

// ---------- 6b. Wigner beta-projection, LDS-staged ----------
__global__ __launch_bounds__(256) void k_so3fft_b(float* ws){
  int bo = blockIdx.x;
  int tid = threadIdx.x;
  __shared__ float xw[722];
  const float* xwbase = ws + OFF_Z + (size_t)bo*32*1024;
  const int* lutA = (const int*)(ws + OFF_LUTA);
  const int* lutB = (const int*)(ws + OFF_LUTB);
  float accr[6], acci[6];
  int la[6], xi2[6], tl2v[6];
  #pragma unroll
  for (int j = 0; j < 6; ++j){
    accr[j] = 0.f; acci[j] = 0.f;
    int q = tid + 256*j;
    if (q < 1330){ la[j] = lutA[q]; int lb = lutB[q]; xi2[j] = 2*(lb & 511); tl2v[j] = (lb >> 9) & 1023; }
    else { la[j] = 0; xi2[j] = 0; tl2v[j] = 0; }
  }
  for (int pp = 0; pp < 32; ++pp){
    __syncthreads();
    for (int u = tid; u < 722; u += 256) xw[u] = xwbase[pp*1024 + u];
    __syncthreads();
    #pragma unroll
    for (int j = 0; j < 6; ++j){
      int q = tid + 256*j;
      if (q < 1330){
        float d = ws[OFF_DMID + la[j] + pp*tl2v[j]];
        accr[j] += d*xw[xi2[j]]; acci[j] += d*xw[xi2[j]+1];
      }
    }
  }
  #pragma unroll
  for (int j = 0; j < 6; ++j){
    int q = tid + 256*j;
    if (q < 1330){
      int base = OFF_XHAT2 + (bo*1330 + q)*2;
      ws[base]   = accr[j];
      ws[base+1] = acci[j];
    }
  }
}

// ---------- 7a. W[i][o][ni] (R3 layout: coalesced both sides) ----------
__global__ void k_wconv(float* ws, const float* __restrict__ w_so3, float scale2){
  int t = blockIdx.x*blockDim.x + threadIdx.x;
  if (t >= 100*100*19) return;
  int ni = t % 19, io = t / 19;
  int n = ni - 9;
  float sr = 0.f, si = 0.f;
  for (int j = 0; j < 32; ++j){
    int k = (j*n) & 31;
    float c = cospif(k/16.0f), s = sinpif(k/16.0f);
    float v = w_so3[io*32 + j] * scale2;
    sr += v*c; si += v*s;
  }
  ws[OFF_WCONV + t*2]   = sr;
  ws[OFF_WCONV + t*2+1] = si;
}

// ---------- 7b. S[b][i][q] = xhat2 . d_eq (R3 layout: coalesced both sides) ----------
__global__ void k_S(float* ws){
  int t = blockIdx.x*blockDim.x + threadIdx.x;
  if (t >= NBATCH*100*1330) return;
  int q = t % 1330, bi = t / 1330;
  int l = 0; while (S2d(l+1) <= q) ++l;
  int loc = q - S2d(l), tl = 2*l+1;
  int mm = loc/tl, nn = loc%tl;
  float sr = 0.f, si = 0.f;
  int xbase = OFF_XHAT2 + (bi*1330 + S2d(l) + mm*tl)*2;
  int dbase = OFF_DEQ + S2d(l) + nn*tl;
  for (int k = 0; k < tl; ++k){
    float d = ws[dbase + k];
    sr += d * ws[xbase + 2*k];
    si += d * ws[xbase + 2*k + 1];
  }
  ws[OFF_SBUF + t*2]   = sr;
  ws[OFF_SBUF + t*2+1] = si;
}

// ---------- 7c. zhat2 = S . W over i (R3: thread per (bo,q), coalesced S reads) ----------
__global__ void k_zhat2(float* ws){
  int t = blockIdx.x*blockDim.x + threadIdx.x;
  if (t >= NBATCH*100*1330) return;
  int q = t % 1330, bo = t / 1330;
  int o = bo % 100, b = bo / 100;
  int lb = ((const int*)(ws+OFF_LUTB))[q];
  int ni = (lb >> 19) & 31;
  const float* sp = ws + OFF_SBUF + (size_t)(b*100)*2660 + 2*q;
  const float* wp = ws + OFF_WCONV + (size_t)(o*19 + ni)*2;
  float sr = 0.f, si = 0.f;
  for (int i = 0; i < 100; ++i){
    float Sr = sp[0], Si = sp[1];
    float Wr = wp[0], Wi = wp[1];
    sr += Sr*Wr - Si*Wi;
    si += Sr*Wi + Si*Wr;
    sp += 2660;
    wp += 3800;   // 100*19*2
  }
  ws[OFF_ZHAT2 + ((size_t)bo*1330 + q)*2]     = sr;
  ws[OFF_ZHAT2 + ((size_t)bo*1330 + q)*2 + 1] = si;
}

// ---------- 8. SO(3) IFFT (b=10), Hermitian + radix-2 ----------
__global__ __launch_bounds__(256) void k_so3ifft_out(float* ws, const float* __restrict__ b_so3){
  int bid = blockIdx.x;
  int p = bid % 20, bo = bid / 20;
  int o = bo % F2C, b = bo / F2C;
  __shared__ __align__(16) float zh[2660];
  __shared__ float Fg[380], tmpS[400];
  __shared__ float twr[20], twi[20], redA[4], redB[4];
  int tid = threadIdx.x;
  {
    const float4* zsrc = (const float4*)(ws + OFF_ZHAT2 + (size_t)(b*100+o)*2660);
    float4* zds = (float4*)zh;
    for (int q = tid; q < 665; q += 256) zds[q] = zsrc[q];
  }
  if (tid < 20){ twr[tid] = cospif(tid/10.0f); twi[tid] = sinpif(tid/10.0f); }
  __syncthreads();
  for (int q = tid; q < 190; q += 256){
    int m = q/19, ni = q%19, n = ni-9;
    int an = n < 0 ? -n : n;
    int lmin = m > an ? m : an;
    float ar = 0.f, ai = 0.f;
    for (int l = lmin; l < 10; ++l){
      int tl = 2*l+1;
      float d = ws[OFF_DOUT + 20*S2d(l) + (p*tl + (m+l))*tl + (n+l)] * (float)tl;
      int fz = S2d(l) + (m+l)*tl + (n+l);
      ar += d*zh[2*fz]; ai += d*zh[2*fz+1];
    }
    Fg[2*q] = ar; Fg[2*q+1] = ai;
  }
  __syncthreads();
  for (int q = tid; q < 100; q += 256){
    int m = q/10, g = q%10;
    float Er=0.f, Ei=0.f, Or=0.f, Oi=0.f;
    int base = 2*m*19;
    for (int ni = 1; ni < 19; ni += 2){
      int n = ni-9;
      int k = ((n*g) % 20 + 20) % 20;
      float c = twr[k], s = twi[k];
      float fr = Fg[base+2*ni], fi = Fg[base+2*ni+1];
      Er += fr*c - fi*s; Ei += fr*s + fi*c;
    }
    for (int ni = 0; ni < 19; ni += 2){
      int n = ni-9;
      int k = ((n*g) % 20 + 20) % 20;
      float c = twr[k], s = twi[k];
      float fr = Fg[base+2*ni], fi = Fg[base+2*ni+1];
      Or += fr*c - fi*s; Oi += fr*s + fi*c;
    }
    tmpS[2*(m*20+g)]      = Er+Or; tmpS[2*(m*20+g)+1]      = Ei+Oi;
    tmpS[2*(m*20+g+10)]   = Er-Or; tmpS[2*(m*20+g+10)+1]   = Ei-Oi;
  }
  __syncthreads();
  float bsv = b_so3[o];
  float lsum = 0.f, lss = 0.f;
  float* z2 = ws + OFF_Z2;
  size_t zb = ((size_t)(b*100+o)*20 + p)*400;
  for (int q = tid; q < 200; q += 256){
    int a = q/20, g = q%20;
    float E = 0.f, O = 0.f;
    for (int m = 2; m < 10; m += 2){
      int k = (m*a) % 20;
      E += tmpS[2*(m*20+g)]*twr[k] - tmpS[2*(m*20+g)+1]*twi[k];
    }
    for (int m = 1; m < 10; m += 2){
      int k = (m*a) % 20;
      O += tmpS[2*(m*20+g)]*twr[k] - tmpS[2*(m*20+g)+1]*twi[k];
    }
    float t0 = tmpS[2*g];
    float v1 = (t0 + 2.0f*(E+O))*(1.0f/400.0f) + bsv;
    float v2 = (t0 + 2.0f*(E-O))*(1.0f/400.0f) + bsv;
    z2[zb + a*20 + g]       = v1;
    z2[zb + (a+10)*20 + g]  = v2;
    lsum += v1+v2; lss += v1*v1+v2*v2;
  }
  for (int off = 32; off; off >>= 1){ lsum += __shfl_down(lsum, off); lss += __shfl_down(lss, off); }
  if ((tid & 63) == 0){ redA[tid>>6] = lsum; redB[tid>>6] = lss; }
  __syncthreads();
  if (tid == 0){
    atomicAdd(&ws[OFF_BN2 + o],       redA[0]+redA[1]+redA[2]+redA[3]);
    atomicAdd(&ws[OFF_BN2 + 100 + o], redB[0]+redB[1]+redB[2]+redB[3]);
  }
}

__global__ void k_bnfin2(float* ws, const float* __restrict__ g2, const float* __restrict__ be2){
  int t = threadIdx.x;
  if (t >= 100) return;
  const float invN = 1.0f/64000.0f;
  float mu = ws[OFF_BN2+t]*invN;
  float var = ws[OFF_BN2+100+t]*invN - mu*mu;
  float sA = rsqrtf(var + 1e-5f) * g2[t];
  ws[OFF_BN2AB+t]     = sA;
  ws[OFF_BN2AB+100+t] = be2[t] - mu*sA;
}

// ---------- 9. final pooling ----------
__global__ __launch_bounds__(256) void k_final(float* ws, float* __restrict__ out){
  int bid = blockIdx.x;
  int c = bid % 100, b = bid / 100;
  int tid = threadIdx.x;
  float sA = ws[OFF_BN2AB+c], sB = ws[OFF_BN2AB+100+c];
  const float* z2 = ws + OFF_Z2 + (size_t)(b*100+c)*8000;
  float lsum = 0.f;
  for (int q = tid; q < 8000; q += 256){
    int p = q / 400;
    float v = z2[q]*sA + sB;
    v = v > 0.f ? v : 0.f;
    lsum += v * ws[OFF_WOUTQ + p];
  }
  for (int off = 32; off; off >>= 1) lsum += __shfl_down(lsum, off);
  __shared__ float red[4];
  if ((tid & 63) == 0) red[tid>>6] = lsum;
  __syncthreads();
  if (tid == 0) out[b*100 + c] = red[0]+red[1]+red[2]+red[3];
}

extern "C" void kernel_launch(void* const* d_in, const int* in_sizes, int n_in,
                              void* d_out, int out_size, void* d_ws, size_t ws_size,
                              hipStream_t stream){
  const float* x      = (const float*)d_in[0];
  const float* w_s2   = (const float*)d_in[1];
  const float* b_s2   = (const float*)d_in[2];
  const float* g1     = (const float*)d_in[3];
  const float* be1    = (const float*)d_in[4];
  const float* w_so3  = (const float*)d_in[5];
  const float* b_so3  = (const float*)d_in[6];
  const float* g2     = (const float*)d_in[7];
  const float* be2    = (const float*)d_in[8];
  float* ws  = (float*)d_ws;
  float* out = (float*)d_out;

  hipMemsetAsync(ws + OFF_IMG, 0, NBATCH*3600*sizeof(float), stream);
  hipMemsetAsync(ws + OFF_BN1, 0, 200*sizeof(float), stream);
  hipMemsetAsync(ws + OFF_BN2, 0, 200*sizeof(float), stream);

  k_quad<<<1, 128, 0, stream>>>(ws);
  k_lut<<<6, 256, 0, stream>>>(ws);
  k_wigner<<<(N_WIG + 255)/256, 256, 0, stream>>>(ws);
  k_project<<<(NBATCH*NPTS + 255)/256, 256, 0, stream>>>(x, ws);
  k_s2dft<<<(NBATCH*60*31 + 255)/256, 256, 0, stream>>>(ws);
  k_xhat<<<(NBATCH*256 + 255)/256, 256, 0, stream>>>(ws);
  float scale1 = (float)(1.0/sqrt(60.0*1.0*65536.0/900.0));
  k_ws2<<<(100*31 + 255)/256, 256, 0, stream>>>(ws, w_s2, scale1);
  k_so3ifft_mid<<<NBATCH*F1C*32, 256, 0, stream>>>(ws, b_s2);
  k_bnfin1<<<1, 128, 0, stream>>>(ws, g1, be1);
  k_so3fft_a<<<NBATCH*F1C*32, 256, 0, stream>>>(ws);
  k_so3fft_b<<<NBATCH*F1C, 256, 0, stream>>>(ws);
  float scale2 = (float)(1.0/sqrt(32.0*100.0*1000.0/4096.0));
  k_wconv<<<(100*100*19 + 255)/256, 256, 0, stream>>>(ws, w_so3, scale2);
  k_S<<<(NBATCH*100*1330 + 255)/256, 256, 0, stream>>>(ws);
  k_zhat2<<<(NBATCH*100*1330 + 255)/256, 256, 0, stream>>>(ws);
  k_so3ifft_out<<<NBATCH*F2C*20, 256, 0, stream>>>(ws, b_so3);
  k_bnfin2<<<1, 128, 0, stream>>>(ws, g2, be2);
  k_final<<<NBATCH*100, 256, 0, stream>>>(ws, out);
}

// Round 8
// 585.750 us; speedup vs baseline: 1.2903x; 1.1478x over previous
//
#include <hip/hip_runtime.h>
#include <math.h>

#define PI_D 3.14159265358979323846

constexpr int NBATCH = 8;
constexpr int NPTS   = 2048;
constexpr int F1C    = 100;
constexpr int F2C    = 100;

__host__ __device__ constexpr int S2c(int l){ return l*(2*l-1)*(2*l+1)/3; }

// ---- workspace layout (float offsets) ----
constexpr int OFF_WIN   = 0;                          // 60
constexpr int OFF_WMID  = OFF_WIN + 60;               // 32
constexpr int OFF_WOUTQ = OFF_WMID + 32;              // 20
constexpr int OFF_DM0W  = OFF_WOUTQ + 20;             // 60*256
constexpr int OFF_DMID  = OFF_DM0W + 60*256;          // 32*S2c(16)
constexpr int OFF_DOUT  = OFF_DMID + 32*S2c(16);      // 20*S2c(10)
constexpr int OFF_DEQ   = OFF_DOUT + 20*S2c(10);      // S2c(16)
constexpr int OFF_IMG   = OFF_DEQ + S2c(16);          // 8*60*60
constexpr int OFF_XF    = OFF_IMG + NBATCH*60*60;     // 8*60*31*2
constexpr int OFF_XHAT  = OFF_XF + NBATCH*60*31*2;    // 8*256*2
constexpr int OFF_WS2   = OFF_XHAT + NBATCH*256*2;    // 100*31*2
constexpr int OFF_BN1   = OFF_WS2 + 100*31*2;         // 200
constexpr int OFF_BN1AB = OFF_BN1 + 200;              // 200
constexpr int OFF_BN2   = OFF_BN1AB + 200;            // 200
constexpr int OFF_BN2AB = OFF_BN2 + 200;              // 200
constexpr int OFF_LUTA  = OFF_BN2AB + 200;            // 1330 ints
constexpr int OFF_LUTB  = OFF_LUTA + 1330;            // 1330 ints: xi | tl2<<9 | ni<<19
constexpr int OFF_WCONV = OFF_LUTB + 1330;            // W[i][o][ni][2]
constexpr int OFF_XHAT2 = OFF_WCONV + 100*100*19*2;   // 8*100*1330*2
constexpr int OFF_SBUF  = OFF_XHAT2 + NBATCH*100*S2c(10)*2;  // S[b][i][q][2]
constexpr int OFF_ZHAT2 = OFF_SBUF + NBATCH*100*S2c(10)*2;
constexpr int OFF_Z2    = OFF_ZHAT2 + NBATCH*100*S2c(10)*2;  // 8*100*8000
constexpr int OFF_Z     = OFF_Z2 + NBATCH*100*20*20*20;      // 8*100*32768
constexpr int WS_TOTAL  = OFF_Z + NBATCH*100*32*32*32;

__device__ __forceinline__ int S2d(int l){ return l*(2*l-1)*(2*l+1)/3; }

// ---------- init: quadrature weights ----------
__global__ void k_quad(float* ws){
  int j = threadIdx.x;
  if (j < 60){
    double bb = 30.0, s = 0.0;
    for (int k = 0; k < 30; ++k) s += sin(PI_D*(2*j+1)*(2*k+1)/(4.0*bb))/(2*k+1);
    ws[OFF_WIN+j] = (float)(2.0/bb * sin(PI_D*(2*j+1)/(4.0*bb)) * s);
  }
  if (j < 32){
    double bb = 16.0, s = 0.0;
    for (int k = 0; k < 16; ++k) s += sin(PI_D*(2*j+1)*(2*k+1)/(4.0*bb))/(2*k+1);
    ws[OFF_WMID+j] = (float)(2.0/bb * sin(PI_D*(2*j+1)/(4.0*bb)) * s);
  }
  if (j < 20){
    double bb = 10.0, s = 0.0;
    for (int k = 0; k < 10; ++k) s += sin(PI_D*(2*j+1)*(2*k+1)/(4.0*bb))/(2*k+1);
    ws[OFF_WOUTQ+j] = (float)(2.0/bb * sin(PI_D*(2*j+1)/(4.0*bb)) * s);
  }
}

// ---------- init: LUT ----------
__global__ void k_lut(float* ws){
  int q = blockIdx.x*blockDim.x + threadIdx.x;
  if (q >= 1330) return;
  int l = 0; while (S2d(l+1) <= q) ++l;
  int loc = q - S2d(l), tl = 2*l+1;
  int mm = loc/tl, nn = loc%tl;
  ((int*)(ws+OFF_LUTA))[q] = 32*S2d(l) + mm*tl + nn;
  ((int*)(ws+OFF_LUTB))[q] = ((mm-l+9)*19 + (nn-l+9)) | ((tl*tl) << 9) | ((nn-l+9) << 19);
}

// ---------- init: Wigner-d tables (factorial table + incremental powers) ----------
__device__ double dev_wigner_t(const double* fact, int l, int mp, int m, double beta){
  double ch = cos(0.5*beta), sh = sin(0.5*beta);
  int kmin = m - mp; if (kmin < 0) kmin = 0;
  int kmax = l + m; if (l - mp < kmax) kmax = l - mp;
  double pref = sqrt(fact[l+mp]*fact[l-mp]*fact[l+m]*fact[l-m]);
  int ec = 2*l + m - mp - 2*kmin, es = mp - m + 2*kmin;
  double cp = 1.0, sp = 1.0;
  for (int e = 0; e < ec; ++e) cp *= ch;
  for (int e = 0; e < es; ++e) sp *= sh;
  double ch2i = 1.0/(ch*ch), sh2 = sh*sh;
  double sum = 0.0;
  for (int k = kmin; k <= kmax; ++k){
    double t = 1.0/(fact[l+m-k]*fact[k]*fact[l-mp-k]*fact[mp-m+k]);
    if ((mp-m+k) & 1) t = -t;
    sum += t*cp*sp;
    cp *= ch2i; sp *= sh2;
  }
  return pref*sum;
}

constexpr int N_DM0W = 60*256;
constexpr int N_DMID = 32*S2c(16);
constexpr int N_DOUT = 20*S2c(10);
constexpr int N_DEQ  = S2c(16);
constexpr int N_WIG  = N_DM0W + N_DMID + N_DOUT + N_DEQ;

__global__ void k_wigner(float* ws){
  __shared__ double fact[32];
  if (threadIdx.x == 0){ fact[0] = 1.0; for (int i = 1; i < 32; ++i) fact[i] = fact[i-1]*i; }
  __syncthreads();
  int idx = blockIdx.x*blockDim.x + threadIdx.x;
  if (idx >= N_WIG) return;
  if (idx < N_DM0W){
    int l = 0; while (60*(l+1)*(l+1) <= idx) ++l;
    int rem = idx - 60*l*l, tl = 2*l+1;
    int p = rem/tl, mm = rem%tl;
    double beta = (p+0.5)*PI_D/60.0;
    ws[OFF_DM0W+idx] = (float)dev_wigner_t(fact, l, mm-l, 0, beta) * ws[OFF_WIN+p];
    return;
  }
  idx -= N_DM0W;
  if (idx < N_DMID){
    int l = 0; while (32*S2d(l+1) <= idx) ++l;
    int rem = idx - 32*S2d(l), tl = 2*l+1;
    int q = rem % (tl*tl), p = rem/(tl*tl);
    int mm = q/tl, nn = q%tl;
    double beta = (p+0.5)*PI_D/32.0;
    ws[OFF_DMID + idx + N_DM0W - N_DM0W + 0] = 0.0f; // placeholder overwritten below
    ws[OFF_DMID+idx] = (float)dev_wigner_t(fact, l, mm-l, nn-l, beta);
    return;
  }
  idx -= N_DMID;
  if (idx < N_DOUT){
    int l = 0; while (20*S2d(l+1) <= idx) ++l;
    int rem = idx - 20*S2d(l), tl = 2*l+1;
    int q = rem % (tl*tl), p = rem/(tl*tl);
    int mm = q/tl, nn = q%tl;
    double beta = (p+0.5)*PI_D/20.0;
    ws[OFF_DOUT+idx] = (float)dev_wigner_t(fact, l, mm-l, nn-l, beta);
    return;
  }
  idx -= N_DOUT;
  {
    int l = 0; while (S2d(l+1) <= idx) ++l;
    int rem = idx - S2d(l), tl = 2*l+1;
    int mm = rem/tl, nn = rem%tl;
    ws[OFF_DEQ+idx] = (float)dev_wigner_t(fact, l, mm-l, nn-l, 0.5*PI_D);
  }
}

// ---------- 1. projection ----------
__global__ void k_project(const float* __restrict__ x, float* ws){
  int t = blockIdx.x*blockDim.x + threadIdx.x;
  if (t >= NBATCH*NPTS) return;
  int b = t / NPTS, n = t % NPTS;
  const float* xb = x + (size_t)b*3*NPTS;
  float xx = xb[n], yy = xb[NPTS+n], zz = xb[2*NPTS+n];
  float r = sqrtf(xx*xx + yy*yy + zz*zz + 1e-12f);
  float ct = zz / r;
  ct = fminf(fmaxf(ct, -1.0f + 1e-7f), 1.0f - 1e-7f);
  float beta = acosf(ct);
  float alpha = atan2f(yy, xx);
  if (alpha < 0.0f) alpha += 2.0f*(float)PI_D;
  int jb = (int)((beta / (float)PI_D) * 60.0f);
  jb = jb < 0 ? 0 : (jb > 59 ? 59 : jb);
  int ja = (int)((alpha / (2.0f*(float)PI_D)) * 60.0f);
  ja = ja < 0 ? 0 : (ja > 59 ? 59 : ja);
  unsigned* img = (unsigned*)(ws + OFF_IMG) + (b*3600 + jb*60 + ja);
  atomicMax(img, __float_as_uint(r));
}

// ---------- 2. S2 DFT over alpha ----------
__global__ void k_s2dft(float* ws){
  int t = blockIdx.x*blockDim.x + threadIdx.x;
  if (t >= NBATCH*60*31) return;
  int b = t/(60*31), r = t%(60*31);
  int p = r/31, mi = r%31, m = mi - 15;
  const float* img = ws + OFF_IMG + (b*60 + p)*60;
  float sr = 0.f, si = 0.f;
  for (int a = 0; a < 60; ++a){
    int k = ((a*m) % 60 + 60) % 60;
    float c = cospif(k/30.0f), s = sinpif(k/30.0f);
    float v = img[a];
    sr += v*c; si -= v*s;
  }
  ws[OFF_XF + t*2]   = sr;
  ws[OFF_XF + t*2+1] = si;
}

// ---------- 3. xhat ----------
__global__ void k_xhat(float* ws){
  int t = blockIdx.x*blockDim.x + threadIdx.x;
  if (t >= NBATCH*256) return;
  int b = t/256, flat = t%256;
  int l = 0; while ((l+1)*(l+1) <= flat) ++l;
  int mm = flat - l*l, tl = 2*l+1;
  int mi = mm - l + 15;
  float sr = 0.f, si = 0.f;
  for (int p = 0; p < 60; ++p){
    float w = ws[OFF_DM0W + 60*l*l + p*tl + mm];
    sr += w * ws[OFF_XF + ((b*60+p)*31 + mi)*2];
    si += w * ws[OFF_XF + ((b*60+p)*31 + mi)*2 + 1];
  }
  ws[OFF_XHAT + t*2]   = sr;
  ws[OFF_XHAT + t*2+1] = si;
}

// ---------- 3b. Ws2 ----------
__global__ void k_ws2(float* ws, const float* __restrict__ w_s2, float scale1){
  int t = blockIdx.x*blockDim.x + threadIdx.x;
  if (t >= 100*31) return;
  int o = t/31, ni = t%31, n = ni - 15;
  float sr = 0.f, si = 0.f;
  for (int k = 0; k < 60; ++k){
    int kk = ((k*n) % 60 + 60) % 60;
    float c = cospif(kk/30.0f), s = sinpif(kk/30.0f);
    float v = w_s2[o*60 + k] * scale1;
    sr += v*c; si += v*s;
  }
  ws[OFF_WS2 + t*2]   = sr;
  ws[OFF_WS2 + t*2+1] = si;
}

// ---------- 4. fused zhat + SO(3) IFFT (b=16): beta-paired (p,31-p), Hermitian + radix-4 ----------
// H[m][n] = sum_l d^l_mn(beta_p) * (2l+1)*d^l_n0(pi/2) * xh[l][m]
// Fg_p[m][n] = W[n]*H[m][n];  Fg_{31-p}[m][-n] = (-1)^m * conj(W[n]) * H[m][n]
__global__ __launch_bounds__(256) void k_so3ifft_mid(float* ws, const float* __restrict__ b_s2){
  int bid = blockIdx.x;
  int p0 = bid & 15, bo = bid >> 4;
  int o = bo % F1C, b = bo / F1C;
  int p1 = 31 - p0;
  __shared__ float xh[512], Dt[256], Hb[992], Fg[992], tmpS[1024];
  __shared__ float twr[32], twi[32], Wr[31], Wi[31], redA[4], redB[4];
  __shared__ int dbase[16];
  int tid = threadIdx.x;
  {
    int flat = tid;
    int l = 0; while ((l+1)*(l+1) <= flat) ++l;
    int mm = flat - l*l, tl = 2*l+1;
    xh[2*flat]   = ws[OFF_XHAT + (b*256+flat)*2];
    xh[2*flat+1] = ws[OFF_XHAT + (b*256+flat)*2+1];
    Dt[flat] = (float)tl * ws[OFF_DEQ + S2d(l) + mm*tl + l];
  }
  if (tid < 32){ twr[tid] = cospif(tid/16.0f); twi[tid] = sinpif(tid/16.0f); }
  if (tid < 31){ Wr[tid] = ws[OFF_WS2 + (o*31+tid)*2]; Wi[tid] = ws[OFF_WS2 + (o*31+tid)*2+1]; }
  if (tid < 16){ int l = tid, tl = 2*l+1; dbase[l] = OFF_DMID + 32*S2d(l) + p0*tl*tl; }
  __syncthreads();
  // H[m][ni], m=0..15
  for (int q = tid; q < 496; q += 256){
    int m = q/31, ni = q%31, n = ni-15;
    int an = n < 0 ? -n : n;
    int lmin = m > an ? m : an;
    float ar = 0.f, ai = 0.f;
    for (int l = lmin; l < 16; ++l){
      int tl = 2*l+1;
      float d = ws[dbase[l] + (m+l)*tl + (n+l)];
      float t = d * Dt[l*l + (n+l)];
      int fa = l*l + (m+l);
      ar += t*xh[2*fa]; ai += t*xh[2*fa+1];
    }
    Hb[2*q] = ar; Hb[2*q+1] = ai;
  }
  __syncthreads();
  float bsv = b_s2[o];
  float lsum = 0.f, lss = 0.f;
  float* z = ws + OFF_Z;
  for (int ph = 0; ph < 2; ++ph){
    int p = ph ? p1 : p0;
    // build Fg for this slab
    for (int q = tid; q < 496; q += 256){
      int m = q/31, ni = q%31;
      float hr = Hb[2*q], hi = Hb[2*q+1];
      float wr = Wr[ni], wi = Wi[ni];
      if (ph == 0){
        Fg[2*q]   = hr*wr - hi*wi;
        Fg[2*q+1] = hr*wi + hi*wr;
      } else {
        float gr = hr*wr + hi*wi;
        float gi = hi*wr - hr*wi;
        if (m & 1){ gr = -gr; gi = -gi; }
        int qd = m*31 + (30-ni);
        Fg[2*qd] = gr; Fg[2*qd+1] = gi;
      }
    }
    __syncthreads();
    // alpha-pass radix-4: g = g0 + 8s, w^{8n} = i^n. 128 threads: (m, g0).
    if (tid < 128){
      int m = tid >> 3, g0 = tid & 7;
      float T0r=0,T0i=0,T1r=0,T1i=0,T2r=0,T2i=0,T3r=0,T3i=0;
      int base = 2*m*31;
      #pragma unroll
      for (int ni = 0; ni < 31; ++ni){
        int k = ((ni-15)*g0) & 31;
        float c = twr[k], s = twi[k];
        float fr = Fg[base+2*ni], fi = Fg[base+2*ni+1];
        float re = fr*c - fi*s, im = fr*s + fi*c;
        int cc = (ni+1) & 3;
        if (cc == 0){ T0r += re; T0i += im; }
        else if (cc == 1){ T1r += re; T1i += im; }
        else if (cc == 2){ T2r += re; T2i += im; }
        else { T3r += re; T3i += im; }
      }
      float Ar=T0r+T2r, Ai=T0i+T2i, Br=T0r-T2r, Bi=T0i-T2i;
      float Cr=T1r+T3r, Ci=T1i+T3i, Dr=T1r-T3r, Di=T1i-T3i;
      int ix = 2*(m*32+g0);
      tmpS[ix]      = Ar+Cr; tmpS[ix+1]    = Ai+Ci;
      tmpS[ix+16]   = Br-Di; tmpS[ix+17]   = Bi+Dr;
      tmpS[ix+32]   = Ar-Cr; tmpS[ix+33]   = Ai-Ci;
      tmpS[ix+48]   = Br+Di; tmpS[ix+49]   = Bi-Dr;
    }
    __syncthreads();
    // gamma-pass radix-4: 256 threads, 4 outputs each
    {
      int a0 = tid >> 5, g = tid & 31;
      float U0r=0, U2r=0, U1r=0, U1i=0, U3r=0, U3i=0;
      #pragma unroll
      for (int m = 1; m < 16; ++m){
        int k = (m*a0) & 31;
        float c = twr[k], s = twi[k];
        float tr = tmpS[2*(m*32+g)], ti = tmpS[2*(m*32+g)+1];
        float re = tr*c - ti*s;
        int cc = m & 3;
        if (cc == 0) U0r += re;
        else if (cc == 2) U2r += re;
        else {
          float im = tr*s + ti*c;
          if (cc == 1){ U1r += re; U1i += im; }
          else        { U3r += re; U3i += im; }
        }
      }
      float Ar = U0r + U2r, Br = U0r - U2r;
      float Cr = U1r + U3r, Di = U1i - U3i;
      float t0 = tmpS[2*g];
      float v0 = (t0 + 2.0f*(Ar + Cr))*(1.0f/1024.0f) + bsv;
      float v1 = (t0 + 2.0f*(Br - Di))*(1.0f/1024.0f) + bsv;
      float v2 = (t0 + 2.0f*(Ar - Cr))*(1.0f/1024.0f) + bsv;
      float v3 = (t0 + 2.0f*(Br + Di))*(1.0f/1024.0f) + bsv;
      size_t zb = ((size_t)(b*F1C+o)*32 + p)*1024;
      z[zb + (a0     )*32 + g] = v0;
      z[zb + (a0 +  8)*32 + g] = v1;
      z[zb + (a0 + 16)*32 + g] = v2;
      z[zb + (a0 + 24)*32 + g] = v3;
      lsum += v0+v1+v2+v3;
      lss  += v0*v0+v1*v1+v2*v2+v3*v3;
    }
    __syncthreads();
  }
  for (int off = 32; off; off >>= 1){ lsum += __shfl_down(lsum, off); lss += __shfl_down(lss, off); }
  if ((tid & 63) == 0){ redA[tid>>6] = lsum; redB[tid>>6] = lss; }
  __syncthreads();
  if (tid == 0){
    atomicAdd(&ws[OFF_BN1 + o],       redA[0]+redA[1]+redA[2]+redA[3]);
    atomicAdd(&ws[OFF_BN1 + 100 + o], redB[0]+redB[1]+redB[2]+redB[3]);
  }
}

__global__ void k_bnfin1(float* ws, const float* __restrict__ g1, const float* __restrict__ be1){
  int t = threadIdx.x;
  if (t >= 100) return;
  const float invN = 1.0f/262144.0f;
  float mu = ws[OFF_BN1+t]*invN;
  float var = ws[OFF_BN1+100+t]*invN - mu*mu;
  float sA = rsqrtf(var + 1e-5f) * g1[t];
  ws[OFF_BN1AB+t]     = sA;
  ws[OFF_BN1AB+100+t] = be1[t] - mu*sA;
}

// ---------- 6a. BN1+ReLU + 2D DFT: radix-4 gamma, Hermitian-halved alpha pass ----------
__global__ __launch_bounds__(256) void k_so3fft_a(float* ws){
  int bid = blockIdx.x;
  int p = bid & 31, bo = bid >> 5;
  int o = bo % F1C;
  __shared__ float y[32*33];
  __shared__ float Bs[32*36];     // per a: [g2*4 + {c0,c2,c1r,c1i}]
  __shared__ float t1[1216];
  __shared__ float twr[32], twi[32];
  int tid = threadIdx.x;
  if (tid < 32){ twr[tid] = cospif(tid/16.0f); twi[tid] = sinpif(tid/16.0f); }
  float sA = ws[OFF_BN1AB+o], sB = ws[OFF_BN1AB+100+o];
  float* zp = ws + OFF_Z + (size_t)bid*1024;
  for (int q = tid; q < 1024; q += 256){
    float v = zp[q]*sA + sB;
    y[(q>>5)*33 + (q&31)] = v > 0.f ? v : 0.f;
  }
  __syncthreads();
  // radix-4 prep over g: B_c[g2], c3 = conj(c1)
  {
    int a = tid >> 3, g2 = tid & 7;
    float y0 = y[a*33+g2], y1 = y[a*33+g2+8], y2 = y[a*33+g2+16], y3 = y[a*33+g2+24];
    float e = y0+y2, f = y1+y3;
    int bb = a*36 + g2*4;
    Bs[bb]   = e+f;
    Bs[bb+1] = e-f;
    Bs[bb+2] = y0-y2;
    Bs[bb+3] = -(y1-y3);
  }
  __syncthreads();
  // pass1: t1[a][ni] for ni=9..18 only (n=0..9); y real => t1[a][-n]=conj(t1[a][n])
  for (int q = tid; q < 320; q += 256){
    int a = q/10, n = q%10, ni = 9+n;
    int c = n & 3;
    int bb = a*36;
    float sr = 0.f, si = 0.f;
    if ((c & 1) == 0){
      int off = bb + (c >> 1);
      #pragma unroll
      for (int g2 = 0; g2 < 8; ++g2){
        int k = (g2*n) & 31;
        float B = Bs[off + g2*4];
        sr += B*twr[k]; si -= B*twi[k];
      }
    } else {
      float sgn = (c == 1) ? 1.f : -1.f;
      #pragma unroll
      for (int g2 = 0; g2 < 8; ++g2){
        int k = (g2*n) & 31;
        float cc_ = twr[k], ss = twi[k];
        float br = Bs[bb+g2*4+2], bi = sgn*Bs[bb+g2*4+3];
        sr += br*cc_ + bi*ss;
        si += bi*cc_ - br*ss;
      }
    }
    t1[2*(a*19+ni)] = sr; t1[2*(a*19+ni)+1] = si;
  }
  __syncthreads();
  // butterfly over a, ni=9..18 only
  for (int q = tid; q < 160; q += 256){
    int a = q/10, ni = 9 + q%10;
    int i0 = 2*(a*19+ni), i1 = 2*((a+16)*19+ni);
    float xr=t1[i0], xi=t1[i0+1], yr=t1[i1], yi=t1[i1+1];
    t1[i0]=xr+yr; t1[i0+1]=xi+yi; t1[i1]=xr-yr; t1[i1+1]=xi-yi;
  }
  __syncthreads();
  // pass3: X2[m][ni] for m=-9..9, ni=9..18; 2D mirror fills the rest
  float wm = ws[OFF_WMID+p];
  for (int q = tid; q < 190; q += 256){
    int m = q/10 - 9, nio = q%10, ni = 9+nio;
    int off = (m & 1) ? 16*19 : 0;
    float sr = 0.f, si = 0.f;
    for (int a = 0; a < 16; ++a){
      int k = (a*m) & 31;
      float c = twr[k], s = twi[k];
      float tr = t1[2*(off+a*19+ni)], ti = t1[2*(off+a*19+ni)+1];
      sr += tr*c + ti*s;
      si += ti*c - tr*s;
    }
    sr *= wm; si *= wm;
    int qf = (m+9)*19 + ni;
    zp[2*qf] = sr; zp[2*qf+1] = si;
    if (nio > 0){
      int qm = (9-m)*19 + (9-nio);
      zp[2*qm] = sr; zp[2*qm+1] = -si;
    }
  }
}

// ---------- 6b. Wigner beta-projection, LDS-staged, 512 threads ----------
__global__ __launch_bounds__(512) void k_so3fft_b(float* ws){
  int bo = blockIdx.x;
  int tid = threadIdx.x;
  __shared__ float xw[722];
  const float* xwbase = ws + OFF_Z + (size_t)bo*32*1024;
  const int* lutA = (const int*)(ws + OFF_LUTA);
  const int* lutB = (const int*)(ws + OFF_LUTB);
  float accr[3], acci[3];
  int la[3], xi2[3], tl2v[3];
  #pragma unroll
  for (int j = 0; j < 3; ++j){
    accr[j] = 0.f; acci[j] = 0.f;
    int q = tid + 512*j;
    if (q < 1330){ la[j] = lutA[q]; int lb = lutB[q]; xi2[j] = 2*(lb & 511); tl2v[j] = (lb >> 9) & 1023; }
    else { la[j] = 0; xi2[j] = 0; tl2v[j] = 0; }
  }
  for (int pp = 0; pp < 32; ++pp){
    __syncthreads();
    for (int u = tid; u < 722; u += 512) xw[u] = xwbase[pp*1024 + u];
    __syncthreads();
    #pragma unroll
    for (int j = 0; j < 3; ++j){
      int q = tid + 512*j;
      if (q < 1330){
        float d = ws[OFF_DMID + la[j] + pp*tl2v[j]];
        accr[j] += d*xw[xi2[j]]; acci[j] += d*xw[xi2[j]+1];
      }
    }
  }
  #pragma unroll
  for (int j = 0; j < 3; ++j){
    int q = tid + 512*j;
    if (q < 1330){
      int base = OFF_XHAT2 + (bo*1330 + q)*2;
      ws[base]   = accr[j];
      ws[base+1] = acci[j];
    }
  }
}

// ---------- 7a. W[i][o][ni] ----------
__global__ void k_wconv(float* ws, const float* __restrict__ w_so3, float scale2){
  int t = blockIdx.x*blockDim.x + threadIdx.x;
  if (t >= 100*100*19) return;
  int ni = t % 19, io = t / 19;
  int n = ni - 9;
  float sr = 0.f, si = 0.f;
  for (int j = 0; j < 32; ++j){
    int k = (j*n) & 31;
    float c = cospif(k/16.0f), s = sinpif(k/16.0f);
    float v = w_so3[io*32 + j] * scale2;
    sr += v*c; si += v*s;
  }
  ws[OFF_WCONV + t*2]   = sr;
  ws[OFF_WCONV + t*2+1] = si;
}

// ---------- 7b. S[b][i][q] = xhat2 . d_eq ----------
__global__ void k_S(float* ws){
  int t = blockIdx.x*blockDim.x + threadIdx.x;
  if (t >= NBATCH*100*1330) return;
  int q = t % 1330, bi = t / 1330;
  int l = 0; while (S2d(l+1) <= q) ++l;
  int loc = q - S2d(l), tl = 2*l+1;
  int mm = loc/tl, nn = loc%tl;
  float sr = 0.f, si = 0.f;
  int xbase = OFF_XHAT2 + (bi*1330 + S2d(l) + mm*tl)*2;
  int dbase = OFF_DEQ + S2d(l) + nn*tl;
  for (int k = 0; k < tl; ++k){
    float d = ws[dbase + k];
    sr += d * ws[xbase + 2*k];
    si += d * ws[xbase + 2*k + 1];
  }
  ws[OFF_SBUF + t*2]   = sr;
  ws[OFF_SBUF + t*2+1] = si;
}

// ---------- 7c. zhat2 = S . W over i ----------
__global__ void k_zhat2(float* ws){
  int t = blockIdx.x*blockDim.x + threadIdx.x;
  if (t >= NBATCH*100*1330) return;
  int q = t % 1330, bo = t / 1330;
  int o = bo % 100, b = bo / 100;
  int lb = ((const int*)(ws+OFF_LUTB))[q];
  int ni = (lb >> 19) & 31;
  const float* sp = ws + OFF_SBUF + (size_t)(b*100)*2660 + 2*q;
  const float* wp = ws + OFF_WCONV + (size_t)(o*19 + ni)*2;
  float sr = 0.f, si = 0.f;
  for (int i = 0; i < 100; ++i){
    float Sr = sp[0], Si = sp[1];
    float Wr = wp[0], Wi = wp[1];
    sr += Sr*Wr - Si*Wi;
    si += Sr*Wi + Si*Wr;
    sp += 2660;
    wp += 3800;
  }
  ws[OFF_ZHAT2 + ((size_t)bo*1330 + q)*2]     = sr;
  ws[OFF_ZHAT2 + ((size_t)bo*1330 + q)*2 + 1] = si;
}

// ---------- 8. SO(3) IFFT (b=10), Hermitian + radix-2 ----------
__global__ __launch_bounds__(256) void k_so3ifft_out(float* ws, const float* __restrict__ b_so3){
  int bid = blockIdx.x;
  int p = bid % 20, bo = bid / 20;
  int o = bo % F2C, b = bo / F2C;
  __shared__ __align__(16) float zh[2660];
  __shared__ float Fg[380], tmpS[400];
  __shared__ float twr[20], twi[20], redA[4], redB[4];
  int tid = threadIdx.x;
  {
    const float4* zsrc = (const float4*)(ws + OFF_ZHAT2 + (size_t)(b*100+o)*2660);
    float4* zds = (float4*)zh;
    for (int q = tid; q < 665; q += 256) zds[q] = zsrc[q];
  }
  if (tid < 20){ twr[tid] = cospif(tid/10.0f); twi[tid] = sinpif(tid/10.0f); }
  __syncthreads();
  for (int q = tid; q < 190; q += 256){
    int m = q/19, ni = q%19, n = ni-9;
    int an = n < 0 ? -n : n;
    int lmin = m > an ? m : an;
    float ar = 0.f, ai = 0.f;
    for (int l = lmin; l < 10; ++l){
      int tl = 2*l+1;
      float d = ws[OFF_DOUT + 20*S2d(l) + (p*tl + (m+l))*tl + (n+l)] * (float)tl;
      int fz = S2d(l) + (m+l)*tl + (n+l);
      ar += d*zh[2*fz]; ai += d*zh[2*fz+1];
    }
    Fg[2*q] = ar; Fg[2*q+1] = ai;
  }
  __syncthreads();
  for (int q = tid; q < 100; q += 256){
    int m = q/10, g = q%10;
    float Er=0.f, Ei=0.f, Or=0.f, Oi=0.f;
    int base = 2*m*19;
    for (int ni = 1; ni < 19; ni += 2){
      int n = ni-9;
      int k = ((n*g) % 20 + 20) % 20;
      float c = twr[k], s = twi[k];
      float fr = Fg[base+2*ni], fi = Fg[base+2*ni+1];
      Er += fr*c - fi*s; Ei += fr*s + fi*c;
    }
    for (int ni = 0; ni < 19; ni += 2){
      int n = ni-9;
      int k = ((n*g) % 20 + 20) % 20;
      float c = twr[k], s = twi[k];
      float fr = Fg[base+2*ni], fi = Fg[base+2*ni+1];
      Or += fr*c - fi*s; Oi += fr*s + fi*c;
    }
    tmpS[2*(m*20+g)]      = Er+Or; tmpS[2*(m*20+g)+1]      = Ei+Oi;
    tmpS[2*(m*20+g+10)]   = Er-Or; tmpS[2*(m*20+g+10)+1]   = Ei-Oi;
  }
  __syncthreads();
  float bsv = b_so3[o];
  float lsum = 0.f, lss = 0.f;
  float* z2 = ws + OFF_Z2;
  size_t zb = ((size_t)(b*100+o)*20 + p)*400;
  for (int q = tid; q < 200; q += 256){
    int a = q/20, g = q%20;
    float E = 0.f, O = 0.f;
    for (int m = 2; m < 10; m += 2){
      int k = (m*a) % 20;
      E += tmpS[2*(m*20+g)]*twr[k] - tmpS[2*(m*20+g)+1]*twi[k];
    }
    for (int m = 1; m < 10; m += 2){
      int k = (m*a) % 20;
      O += tmpS[2*(m*20+g)]*twr[k] - tmpS[2*(m*20+g)+1]*twi[k];
    }
    float t0 = tmpS[2*g];
    float v1 = (t0 + 2.0f*(E+O))*(1.0f/400.0f) + bsv;
    float v2 = (t0 + 2.0f*(E-O))*(1.0f/400.0f) + bsv;
    z2[zb + a*20 + g]       = v1;
    z2[zb + (a+10)*20 + g]  = v2;
    lsum += v1+v2; lss += v1*v1+v2*v2;
  }
  for (int off = 32; off; off >>= 1){ lsum += __shfl_down(lsum, off); lss += __shfl_down(lss, off); }
  if ((tid & 63) == 0){ redA[tid>>6] = lsum; redB[tid>>6] = lss; }
  __syncthreads();
  if (tid == 0){
    atomicAdd(&ws[OFF_BN2 + o],       redA[0]+redA[1]+redA[2]+redA[3]);
    atomicAdd(&ws[OFF_BN2 + 100 + o], redB[0]+redB[1]+redB[2]+redB[3]);
  }
}

__global__ void k_bnfin2(float* ws, const float* __restrict__ g2, const float* __restrict__ be2){
  int t = threadIdx.x;
  if (t >= 100) return;
  const float invN = 1.0f/64000.0f;
  float mu = ws[OFF_BN2+t]*invN;
  float var = ws[OFF_BN2+100+t]*invN - mu*mu;
  float sA = rsqrtf(var + 1e-5f) * g2[t];
  ws[OFF_BN2AB+t]     = sA;
  ws[OFF_BN2AB+100+t] = be2[t] - mu*sA;
}

// ---------- 9. final pooling ----------
__global__ __launch_bounds__(256) void k_final(float* ws, float* __restrict__ out){
  int bid = blockIdx.x;
  int c = bid % 100, b = bid / 100;
  int tid = threadIdx.x;
  float sA = ws[OFF_BN2AB+c], sB = ws[OFF_BN2AB+100+c];
  const float* z2 = ws + OFF_Z2 + (size_t)(b*100+c)*8000;
  float lsum = 0.f;
  for (int q = tid; q < 8000; q += 256){
    int p = q / 400;
    float v = z2[q]*sA + sB;
    v = v > 0.f ? v : 0.f;
    lsum += v * ws[OFF_WOUTQ + p];
  }
  for (int off = 32; off; off >>= 1) lsum += __shfl_down(lsum, off);
  __shared__ float red[4];
  if ((tid & 63) == 0) red[tid>>6] = lsum;
  __syncthreads();
  if (tid == 0) out[b*100 + c] = red[0]+red[1]+red[2]+red[3];
}

extern "C" void kernel_launch(void* const* d_in, const int* in_sizes, int n_in,
                              void* d_out, int out_size, void* d_ws, size_t ws_size,
                              hipStream_t stream){
  const float* x      = (const float*)d_in[0];
  const float* w_s2   = (const float*)d_in[1];
  const float* b_s2   = (const float*)d_in[2];
  const float* g1     = (const float*)d_in[3];
  const float* be1    = (const float*)d_in[4];
  const float* w_so3  = (const float*)d_in[5];
  const float* b_so3  = (const float*)d_in[6];
  const float* g2     = (const float*)d_in[7];
  const float* be2    = (const float*)d_in[8];
  float* ws  = (float*)d_ws;
  float* out = (float*)d_out;

  hipMemsetAsync(ws + OFF_IMG, 0, NBATCH*3600*sizeof(float), stream);
  hipMemsetAsync(ws + OFF_BN1, 0, 200*sizeof(float), stream);
  hipMemsetAsync(ws + OFF_BN2, 0, 200*sizeof(float), stream);

  k_quad<<<1, 128, 0, stream>>>(ws);
  k_lut<<<6, 256, 0, stream>>>(ws);
  k_wigner<<<(N_WIG + 255)/256, 256, 0, stream>>>(ws);
  k_project<<<(NBATCH*NPTS + 255)/256, 256, 0, stream>>>(x, ws);
  k_s2dft<<<(NBATCH*60*31 + 255)/256, 256, 0, stream>>>(ws);
  k_xhat<<<(NBATCH*256 + 255)/256, 256, 0, stream>>>(ws);
  float scale1 = (float)(1.0/sqrt(60.0*1.0*65536.0/900.0));
  k_ws2<<<(100*31 + 255)/256, 256, 0, stream>>>(ws, w_s2, scale1);
  k_so3ifft_mid<<<NBATCH*F1C*16, 256, 0, stream>>>(ws, b_s2);
  k_bnfin1<<<1, 128, 0, stream>>>(ws, g1, be1);
  k_so3fft_a<<<NBATCH*F1C*32, 256, 0, stream>>>(ws);
  k_so3fft_b<<<NBATCH*F1C, 512, 0, stream>>>(ws);
  float scale2 = (float)(1.0/sqrt(32.0*100.0*1000.0/4096.0));
  k_wconv<<<(100*100*19 + 255)/256, 256, 0, stream>>>(ws, w_so3, scale2);
  k_S<<<(NBATCH*100*1330 + 255)/256, 256, 0, stream>>>(ws);
  k_zhat2<<<(NBATCH*100*1330 + 255)/256, 256, 0, stream>>>(ws);
  k_so3ifft_out<<<NBATCH*F2C*20, 256, 0, stream>>>(ws, b_so3);
  k_bnfin2<<<1, 128, 0, stream>>>(ws, g2, be2);
  k_final<<<NBATCH*100, 256, 0, stream>>>(ws, out);
}